// Round 8
// baseline (933.946 us; speedup 1.0000x reference)
//
#include <hip/hip_runtime.h>
#include <hip/hip_bf16.h>

// DynamicJKGCN on MI355X — round 8: gather v3 (half-wave float4 + 2-deep pipeline).
// Round-7 confirmed: fp32 world, MFMA-from-fp32 GEMMs correct (919us, absmax 9.8e-4).
// This round: agg_gather/mean_gather switch from full-wave float2 (1 node/wave)
// to half-wave float4 (2 nodes/wave, 8/block), with the next edge's row load
// issued before the current row's FMA (2 outstanding row loads per chain).
// scatter2 (138us, write-churn) left for round 9 (LDS-staged bucketing).
// Everything else byte-identical to round 7.

#define H_FEATS 128

typedef __attribute__((ext_vector_type(8))) short short8;   // 8 bf16 in 4 VGPRs
typedef __attribute__((ext_vector_type(4))) float float4v;  // 4 fp32 acc

__device__ __forceinline__ float dload(const void* p, size_t i, int isbf) {
    return isbf ? __bfloat162float(((const __hip_bfloat16*)p)[i])
                : ((const float*)p)[i];
}

// ---------------- dtype sniff ----------------
__global__ __launch_bounds__(256) void sniff_dtype(const unsigned int* __restrict__ x,
                                                   int* __restrict__ flag) {
    __shared__ int cnt[256];
    int t = threadIdx.x;
    int c = 0;
    for (int i = 0; i < 16; i++) {
        unsigned int w = x[t * 16 + i];
        unsigned int e = (w >> 7) & 0xFFu;
        c += (e >= 0x60u && e <= 0x8Fu) ? 1 : 0;
    }
    cnt[t] = c;
    __syncthreads();
    for (int s = 128; s > 0; s >>= 1) {
        if (t < s) cnt[t] += cnt[t + s];
        __syncthreads();
    }
    if (t == 0) *flag = (cnt[0] > 3000) ? 1 : 0;
}

// meta[0]=dtype flag (int); meta[8..10]=softmax(jk_weights)
__global__ void compute_jkw(const void* __restrict__ jkwb, float* __restrict__ meta) {
    if (threadIdx.x == 0) {
        int isbf = ((const int*)meta)[0];
        float w0 = dload(jkwb, 0, isbf);
        float w1 = dload(jkwb, 1, isbf);
        float w2 = dload(jkwb, 2, isbf);
        float m = fmaxf(w0, fmaxf(w1, w2));
        float e0 = expf(w0 - m), e1 = expf(w1 - m), e2 = expf(w2 - m);
        float s = e0 + e1 + e2;
        meta[8] = e0 / s; meta[9] = e1 / s; meta[10] = e2 / s;
    }
}

// ---------------- CSR build ----------------
__global__ __launch_bounds__(256) void histo(const int* __restrict__ row, const int* __restrict__ col,
                                             int* __restrict__ cntc, int* __restrict__ cntr, int E) {
    int e = blockIdx.x * 256 + threadIdx.x;
    if (e < E) {
        atomicAdd(&cntc[col[e]], 1);
        atomicAdd(&cntr[row[e]], 1);
    }
}

__global__ __launch_bounds__(256) void dinv_from_cnt(const int* __restrict__ cntc,
                                                     float* __restrict__ dinv, int N) {
    int i = blockIdx.x * 256 + threadIdx.x;
    if (i < N) dinv[i] = rsqrtf(1.0f + (float)cntc[i]);  // +1 self-loop
}

__global__ __launch_bounds__(1024) void scan2(const int* __restrict__ c0, int* __restrict__ o0, int* __restrict__ u0,
                                              const int* __restrict__ c1, int* __restrict__ o1, int* __restrict__ u1,
                                              int N) {
    const int* cnt = blockIdx.x ? c1 : c0;
    int* off = blockIdx.x ? o1 : o0;
    int* cur = blockIdx.x ? u1 : u0;
    __shared__ int part[1024];
    int t = threadIdx.x;
    int chunk = (N + 1023) / 1024;
    int beg = t * chunk;
    int end = beg + chunk; if (end > N) end = N;
    if (beg > N) beg = N;
    int s = 0;
    for (int i = beg; i < end; i++) s += cnt[i];
    part[t] = s;
    __syncthreads();
    for (int d = 1; d < 1024; d <<= 1) {
        int v = (t >= d) ? part[t - d] : 0;
        __syncthreads();
        part[t] += v;
        __syncthreads();
    }
    int base = (t == 0) ? 0 : part[t - 1];
    for (int i = beg; i < end; i++) {
        off[i] = base; cur[i] = base; base += cnt[i];
    }
    if (end == N && beg < N) off[N] = base;
}

__global__ __launch_bounds__(256) void scatter2(const int* __restrict__ row, const int* __restrict__ col,
                                                int* __restrict__ curc, int* __restrict__ curr,
                                                int* __restrict__ ecol, int* __restrict__ erow,
                                                int E, int doRow) {
    int e = blockIdx.x * 256 + threadIdx.x;
    if (e >= E) return;
    int s = row[e], d = col[e];
    int p = atomicAdd(&curc[d], 1);
    ecol[p] = s;
    if (doRow) {
        int q = atomicAdd(&curr[s], 1);
        erow[q] = d;
    }
}

// ---------------- W prepack for MFMA B-fragments (dtype-agnostic) ----------------
__global__ __launch_bounds__(256) void pack_w(const void* __restrict__ W,
                                              unsigned short* __restrict__ Wp,
                                              const int* __restrict__ flagp, int K) {
    int gid = blockIdx.x * 256 + threadIdx.x;
    int steps = K >> 5;
    if (gid >= steps * 8 * 64) return;
    int isbf = *flagp;
    int lane = gid & 63;
    int t = (gid >> 6) & 7;
    int s = gid >> 9;
    int krow = s * 32 + ((lane >> 4) << 3);
    int ncol = t * 16 + (lane & 15);
#pragma unroll
    for (int j = 0; j < 8; j++) {
        float v = dload(W, (size_t)(krow + j) * H_FEATS + ncol, isbf);
        Wp[(size_t)gid * 8 + j] = __bfloat16_as_ushort(__float2bfloat16(v));
    }
}

// ---------------- MFMA GEMM from fp32 input ----------------
template <int K, bool GATED>
__global__ __launch_bounds__(256) void gemm_mfma_f32(const float* __restrict__ X,
                                                     const unsigned short* __restrict__ Wp,
                                                     float* __restrict__ C,
                                                     const int* __restrict__ flagp, int M) {
    if (GATED && *flagp != 0) return;
    const int tid = threadIdx.x;
    const int wave = tid >> 6, lane = tid & 63;
    const int m16 = lane & 15, quad = lane >> 4;
    const int row = blockIdx.x * 64 + wave * 16 + m16;
    constexpr int STEPS = K / 32;

    float4v acc[8];
#pragma unroll
    for (int t = 0; t < 8; t++) acc[t] = (float4v){0.f, 0.f, 0.f, 0.f};

    const bool rowOK = row < M;
#pragma unroll
    for (int s = 0; s < STEPS; s++) {
        int k0 = s * 32 + quad * 8;
        short8 a = (short8)(short)0;
        if (rowOK) {
            const float* p = X + (size_t)row * K + k0;
            float4 f0 = *(const float4*)p;
            float4 f1 = *(const float4*)(p + 4);
            a[0] = (short)__bfloat16_as_ushort(__float2bfloat16(f0.x));
            a[1] = (short)__bfloat16_as_ushort(__float2bfloat16(f0.y));
            a[2] = (short)__bfloat16_as_ushort(__float2bfloat16(f0.z));
            a[3] = (short)__bfloat16_as_ushort(__float2bfloat16(f0.w));
            a[4] = (short)__bfloat16_as_ushort(__float2bfloat16(f1.x));
            a[5] = (short)__bfloat16_as_ushort(__float2bfloat16(f1.y));
            a[6] = (short)__bfloat16_as_ushort(__float2bfloat16(f1.z));
            a[7] = (short)__bfloat16_as_ushort(__float2bfloat16(f1.w));
        }
#pragma unroll
        for (int t = 0; t < 8; t++) {
            short8 b = *(const short8*)(Wp + ((size_t)(s * 8 + t) * 64 + lane) * 8);
            acc[t] = __builtin_amdgcn_mfma_f32_16x16x32_bf16(a, b, acc[t], 0, 0, 0);
        }
    }
#pragma unroll
    for (int r = 0; r < 4; r++) {
        int gr = blockIdx.x * 64 + wave * 16 + quad * 4 + r;
        if (gr < M) {
#pragma unroll
            for (int t = 0; t < 8; t++)
                C[(size_t)gr * H_FEATS + t * 16 + m16] = acc[t][r];
        }
    }
}

// ---------------- gather v3: half-wave (32 lanes x float4) per node ----------------
// hout[d] = relu( sum_{s in Nin(d)} dinv[s]dinv[d] H[s] + dinv[d]^2 H[d] + b )
__global__ __launch_bounds__(256) void agg_gather3(const int* __restrict__ off,
                                                   const int* __restrict__ idx,
                                                   const float* __restrict__ dinv,
                                                   const float* __restrict__ H,
                                                   const void* __restrict__ bv,
                                                   float* __restrict__ hout,
                                                   const int* __restrict__ flagp, int N) {
    int node = blockIdx.x * 8 + (threadIdx.x >> 5);
    if (node >= N) return;
    int l = threadIdx.x & 31;
    int isbf = *flagp;
    int beg = off[node], end = off[node + 1];
    float dd = dinv[node];
    size_t ro = (size_t)l * 4;

    float4 self = *(const float4*)&H[(size_t)node * H_FEATS + ro];
    float w0s = dd * dd;
    float4 acc = {w0s * self.x, w0s * self.y, w0s * self.z, w0s * self.w};

    int i = beg;
    int s0 = (i < end) ? idx[i] : 0;
    float4 h0 = (i < end) ? *(const float4*)&H[(size_t)s0 * H_FEATS + ro]
                          : (float4){0.f, 0.f, 0.f, 0.f};
    for (; i < end; i++) {
        int s1 = (i + 1 < end) ? idx[i + 1] : 0;
        float4 h1 = (i + 1 < end) ? *(const float4*)&H[(size_t)s1 * H_FEATS + ro] : h0;
        float w = dinv[s0] * dd;
        acc.x = fmaf(w, h0.x, acc.x);
        acc.y = fmaf(w, h0.y, acc.y);
        acc.z = fmaf(w, h0.z, acc.z);
        acc.w = fmaf(w, h0.w, acc.w);
        s0 = s1; h0 = h1;
    }
    acc.x = fmaxf(acc.x + dload(bv, l * 4 + 0, isbf), 0.0f);
    acc.y = fmaxf(acc.y + dload(bv, l * 4 + 1, isbf), 0.0f);
    acc.z = fmaxf(acc.z + dload(bv, l * 4 + 2, isbf), 0.0f);
    acc.w = fmaxf(acc.w + dload(bv, l * 4 + 3, isbf), 0.0f);
    *(float4*)&hout[(size_t)node * H_FEATS + ro] = acc;
}

// h0[r] = (odeg>0) ? mean_{c in Nout(r)} h0pre[c] : h0pre[r]
__global__ __launch_bounds__(256) void mean_gather3(const int* __restrict__ off,
                                                    const int* __restrict__ idx,
                                                    const float* __restrict__ Hsrc,
                                                    float* __restrict__ hout, int N) {
    int node = blockIdx.x * 8 + (threadIdx.x >> 5);
    if (node >= N) return;
    int l = threadIdx.x & 31;
    int beg = off[node], end = off[node + 1];
    size_t ro = (size_t)l * 4;

    float4 acc = {0.f, 0.f, 0.f, 0.f};
    int i = beg;
    int s0 = (i < end) ? idx[i] : 0;
    float4 h0 = (i < end) ? *(const float4*)&Hsrc[(size_t)s0 * H_FEATS + ro]
                          : (float4){0.f, 0.f, 0.f, 0.f};
    for (; i < end; i++) {
        int s1 = (i + 1 < end) ? idx[i + 1] : 0;
        float4 h1 = (i + 1 < end) ? *(const float4*)&Hsrc[(size_t)s1 * H_FEATS + ro] : h0;
        acc.x += h0.x; acc.y += h0.y; acc.z += h0.z; acc.w += h0.w;
        s0 = s1; h0 = h1;
    }
    int cnt = end - beg;
    float4 res;
    if (cnt > 0) {
        float inv = 1.0f / (float)cnt;
        res.x = acc.x * inv; res.y = acc.y * inv; res.z = acc.z * inv; res.w = acc.w * inv;
    } else {
        res = *(const float4*)&Hsrc[(size_t)node * H_FEATS + ro];
    }
    *(float4*)&hout[(size_t)node * H_FEATS + ro] = res;
}

// ---------------- fp32 GEMM (tier C + gated bf16 world) ----------------
template <int K, bool XIN, bool GATEBF>
__global__ __launch_bounds__(256) void gemm128(const void* __restrict__ Xv,
                                               const void* __restrict__ Wv,
                                               float* __restrict__ C,
                                               const int* __restrict__ flagp, int N) {
    constexpr int BM = 64, BK = 16, BN = 128, TN = 8, TX = BN / TN;
    __shared__ float Xs[BK][BM + 4];
    __shared__ float Ws[BK][BN];
    const int isbf = *flagp;
    if (GATEBF && isbf != 1) return;
    const float* Xf = (const float*)Xv;

    const int tid = threadIdx.x;
    const int tx = tid % TX;
    const int ty = tid / TX;
    const int rowBase = blockIdx.x * BM;

    float acc[4][TN] = {};
    const int lk = tid % BK;
    const int lr0 = tid / BK;

    for (int kb = 0; kb < K; kb += BK) {
#pragma unroll
        for (int i = 0; i < 4; i++) {
            int r = lr0 + i * 16;
            int gr = rowBase + r;
            float v = 0.0f;
            if (gr < N) {
                size_t idx = (size_t)gr * K + kb + lk;
                v = XIN ? dload(Xv, idx, isbf) : Xf[idx];
            }
            Xs[lk][r] = v;
        }
#pragma unroll
        for (int i = 0; i < 8; i++) {
            int idx = i * 256 + tid;
            int k = idx >> 7, c = idx & 127;
            Ws[k][c] = dload(Wv, (size_t)(kb + k) * BN + c, isbf);
        }
        __syncthreads();
#pragma unroll
        for (int k = 0; k < BK; k++) {
            float4 a = *(const float4*)&Xs[k][ty * 4];
            float av[4] = {a.x, a.y, a.z, a.w};
            float4 b0 = *(const float4*)&Ws[k][tx * TN];
            float4 b1 = *(const float4*)&Ws[k][tx * TN + 4];
            float bv[8] = {b0.x, b0.y, b0.z, b0.w, b1.x, b1.y, b1.z, b1.w};
#pragma unroll
            for (int i = 0; i < 4; i++)
#pragma unroll
                for (int j = 0; j < TN; j++) acc[i][j] = fmaf(av[i], bv[j], acc[i][j]);
        }
        __syncthreads();
    }
#pragma unroll
    for (int i = 0; i < 4; i++) {
        int gr = rowBase + ty * 4 + i;
        if (gr < N) {
#pragma unroll
            for (int j = 0; j < TN; j++) C[(size_t)gr * BN + tx * TN + j] = acc[i][j];
        }
    }
}

template <bool FIRST, bool LAST>
__global__ __launch_bounds__(256) void fc_accum(const float* __restrict__ Hm,
                                                const void* __restrict__ Wv,
                                                const void* __restrict__ bv,
                                                void* __restrict__ Outv,
                                                const float* __restrict__ meta,
                                                int widx, int N) {
    constexpr int BM = 64, BK = 16, BN = 64, TN = 4, TX = BN / TN, K = 128;
    __shared__ float Xs[BK][BM + 4];
    __shared__ float Ws[BK][BN];
    const int isbf = ((const int*)meta)[0];
    const float scale = meta[8 + widx];

    const int tid = threadIdx.x;
    const int tx = tid % TX;
    const int ty = tid / TX;
    const int rowBase = blockIdx.x * BM;

    float acc[4][TN] = {};
    const int lk = tid % BK;
    const int lr0 = tid / BK;

    for (int kb = 0; kb < K; kb += BK) {
#pragma unroll
        for (int i = 0; i < 4; i++) {
            int r = lr0 + i * 16;
            int gr = rowBase + r;
            float v = 0.0f;
            if (gr < N) v = Hm[(size_t)gr * K + kb + lk];
            Xs[lk][r] = v;
        }
#pragma unroll
        for (int i = 0; i < 4; i++) {
            int idx = i * 256 + tid;
            int k = idx >> 6, c = idx & 63;
            Ws[k][c] = dload(Wv, (size_t)(kb + k) * BN + c, isbf);
        }
        __syncthreads();
#pragma unroll
        for (int k = 0; k < BK; k++) {
            float4 a = *(const float4*)&Xs[k][ty * 4];
            float av[4] = {a.x, a.y, a.z, a.w};
            float4 bb = *(const float4*)&Ws[k][tx * TN];
            float bvv[4] = {bb.x, bb.y, bb.z, bb.w};
#pragma unroll
            for (int i = 0; i < 4; i++)
#pragma unroll
                for (int j = 0; j < TN; j++) acc[i][j] = fmaf(av[i], bvv[j], acc[i][j]);
        }
        __syncthreads();
    }
    __hip_bfloat16* ob = (__hip_bfloat16*)Outv;
    float* of = (float*)Outv;
#pragma unroll
    for (int i = 0; i < 4; i++) {
        int gr = rowBase + ty * 4 + i;
        if (gr < N) {
#pragma unroll
            for (int j = 0; j < TN; j++) {
                int c = tx * TN + j;
                size_t o = (size_t)gr * BN + c;
                float v = scale * acc[i][j];
                if (!FIRST) v += isbf ? __bfloat162float(ob[o]) : of[o];
                if (LAST) v += dload(bv, c, isbf);
                if (isbf) ob[o] = __float2bfloat16(v); else of[o] = v;
            }
        }
    }
}

// ---------------- atomic fallbacks (tier B / C) ----------------
__global__ __launch_bounds__(256) void init_deg(float* deg, float* odeg, int N) {
    int i = blockIdx.x * 256 + threadIdx.x;
    if (i < N) { deg[i] = 1.0f; odeg[i] = 0.0f; }
}
__global__ __launch_bounds__(256) void count_deg(const int* __restrict__ row, const int* __restrict__ col,
                                                 float* deg, float* odeg, int E) {
    int e = blockIdx.x * 256 + threadIdx.x;
    if (e < E) {
        atomicAdd(&deg[col[e]], 1.0f);
        atomicAdd(&odeg[row[e]], 1.0f);
    }
}
__global__ __launch_bounds__(256) void deg_to_dinv(float* deg, int N) {
    int i = blockIdx.x * 256 + threadIdx.x;
    if (i < N) deg[i] = rsqrtf(deg[i]);
}
__global__ __launch_bounds__(256) void agg_edges(const int* __restrict__ row, const int* __restrict__ col,
                                                 const float* __restrict__ dinv,
                                                 const float* __restrict__ H,
                                                 float* __restrict__ agg, int E) {
    int e = blockIdx.x * 2 + (threadIdx.x >> 7);
    if (e >= E) return;
    int j = threadIdx.x & 127;
    int s = row[e], d = col[e];
    float w = dinv[s] * dinv[d];
    atomicAdd(&agg[(size_t)d * H_FEATS + j], w * H[(size_t)s * H_FEATS + j]);
}
__global__ __launch_bounds__(256) void mean_edges(const int* __restrict__ row, const int* __restrict__ col,
                                                  const float* __restrict__ h0pre,
                                                  float* __restrict__ nsum, int E) {
    int e = blockIdx.x * 2 + (threadIdx.x >> 7);
    if (e >= E) return;
    int j = threadIdx.x & 127;
    int r = row[e], c = col[e];
    atomicAdd(&nsum[(size_t)r * H_FEATS + j], h0pre[(size_t)c * H_FEATS + j]);
}
__global__ __launch_bounds__(256) void finalize_layer(const float* __restrict__ agg,
                                                      const float* __restrict__ H,
                                                      const float* __restrict__ dinv,
                                                      const void* __restrict__ bv,
                                                      float* __restrict__ hout,
                                                      const int* __restrict__ flagp, int NH) {
    int idx = blockIdx.x * 256 + threadIdx.x;
    if (idx >= NH) return;
    int isbf = *flagp;
    int v = idx >> 7, j = idx & 127;
    float di = dinv[v];
    float h = fmaf(di * di, H[idx], agg[idx]) + dload(bv, j, isbf);
    hout[idx] = fmaxf(h, 0.0f);
}
__global__ __launch_bounds__(256) void finalize_mean(const float* __restrict__ nsum,
                                                     const float* __restrict__ h0pre,
                                                     const float* __restrict__ odeg,
                                                     float* __restrict__ h0, int NH) {
    int idx = blockIdx.x * 256 + threadIdx.x;
    if (idx >= NH) return;
    int v = idx >> 7;
    float od = odeg[v];
    h0[idx] = (od > 0.0f) ? (nsum[idx] / od) : h0pre[idx];
}
__global__ __launch_bounds__(256) void finalize_mean_cnt(const float* __restrict__ nsum,
                                                         const float* __restrict__ h0pre,
                                                         const int* __restrict__ cntr,
                                                         float* __restrict__ h0, int NH) {
    int idx = blockIdx.x * 256 + threadIdx.x;
    if (idx >= NH) return;
    int v = idx >> 7;
    int od = cntr[v];
    h0[idx] = (od > 0) ? (nsum[idx] / (float)od) : h0pre[idx];
}

extern "C" void kernel_launch(void* const* d_in, const int* in_sizes, int n_in,
                              void* d_out, int out_size, void* d_ws, size_t ws_size,
                              hipStream_t stream) {
    const void* x   = d_in[0];
    const int*  ei  = (const int*)d_in[1];
    const void* W1  = d_in[2];
    const void* b1  = d_in[3];
    const void* W2  = d_in[4];
    const void* b2  = d_in[5];
    const void* W3  = d_in[6];
    const void* b3  = d_in[7];
    const void* jkb = d_in[8];
    const void* Wfc = d_in[9];
    const void* bfc = d_in[10];

    const int IN = 256;
    const int N = in_sizes[0] / IN;          // 50000
    const int E = in_sizes[1] / 2;           // 800000
    const int NH = N * H_FEATS;

    const int* row = ei;
    const int* col = ei + E;

    // ---- workspace layout (fp32 words) — round-7 identical ----
    float* ws = (float*)d_ws;
    size_t o = 0;
    float* meta = ws + o;            o += 256;
    float* dinv = ws + o;            o += N;
    int*   cntc = (int*)(ws + o);    o += N;
    int*   cntr = (int*)(ws + o);    o += N;
    int*   coff = (int*)(ws + o);    o += N + 1;
    int*   curc = (int*)(ws + o);    o += N;
    int*   ecol = (int*)(ws + o);    o += E;
    size_t oB_small = o;
    int*   roff = (int*)(ws + o);    o += N + 1;
    int*   curr = (int*)(ws + o);    o += N;
    int*   erow = (int*)(ws + o);    o += E;
    size_t oA_full = o;

    auto alignup = [](size_t v) { return (v + 63) & ~(size_t)63; };
    const size_t WPW = 16384 + 8192 + 8192;
    size_t needA = alignup(oA_full) + 2 * (size_t)NH + 64 + WPW;
    size_t needB = alignup(oB_small) + 2 * (size_t)NH + 64 + WPW;

    int tier;
    size_t hoff;
    if (ws_size >= needA * 4)      { tier = 0; hoff = alignup(oA_full); }
    else if (ws_size >= needB * 4) { tier = 1; hoff = alignup(oB_small); }
    else                           { tier = 2; hoff = alignup(256 + 2 * (size_t)N); }
    float* A = ws + hoff;
    float* B = A + NH;
    size_t wpoff = alignup(hoff + 2 * (size_t)NH);
    unsigned short* Wp1 = (unsigned short*)(ws + wpoff);
    unsigned short* Wp2 = Wp1 + 32768;
    unsigned short* Wp3 = Wp2 + 16384;
    float* odegf = ws + 256 + N;
    const int* flag = (const int*)meta;

    dim3 blk(256);
    int gN = (N + 255) / 256;
    int gE = (E + 255) / 256;
    int gE2 = (E + 1) / 2;
    int gNH = (NH + 255) / 256;
    int gGemm = (N + 63) / 64;
    int gNode8 = (N + 7) / 8;        // gather v3: 8 nodes / 256-block

    sniff_dtype<<<1, blk, 0, stream>>>((const unsigned int*)x, (int*)meta);
    compute_jkw<<<1, 64, 0, stream>>>(jkb, meta);

    if (tier < 2) {
        // ---- CSR build ----
        hipMemsetAsync(cntc, 0, 2 * (size_t)N * 4, stream);
        histo<<<gE, blk, 0, stream>>>(row, col, cntc, cntr, E);
        dinv_from_cnt<<<gN, blk, 0, stream>>>(cntc, dinv, N);
        if (tier == 0) {
            scan2<<<2, 1024, 0, stream>>>(cntc, coff, curc, cntr, roff, curr, N);
            scatter2<<<gE, blk, 0, stream>>>(row, col, curc, curr, ecol, erow, E, 1);
        } else {
            scan2<<<1, 1024, 0, stream>>>(cntc, coff, curc, cntc, coff, curc, N);
            scatter2<<<gE, blk, 0, stream>>>(row, col, curc, curc, ecol, ecol, E, 0);
        }

        // ---- W prepack ----
        pack_w<<<16, blk, 0, stream>>>(W1, Wp1, flag, 256);
        pack_w<<<8, blk, 0, stream>>>(W2, Wp2, flag, 128);
        pack_w<<<8, blk, 0, stream>>>(W3, Wp3, flag, 128);

        // ---- layer 0 ----
        gemm128<256, true, true><<<gGemm, blk, 0, stream>>>(x, W1, A, flag, N);
        gemm_mfma_f32<256, true><<<gGemm, blk, 0, stream>>>((const float*)x, Wp1, A, flag, N);
        agg_gather3<<<gNode8, blk, 0, stream>>>(coff, ecol, dinv, A, b1, B, flag, N);
        if (tier == 0) {
            mean_gather3<<<gNode8, blk, 0, stream>>>(roff, erow, B, A, N);
        } else {
            hipMemsetAsync(A, 0, (size_t)NH * 4, stream);
            mean_edges<<<gE2, blk, 0, stream>>>(row, col, B, A, E);
            finalize_mean_cnt<<<gNH, blk, 0, stream>>>(A, B, cntr, A, NH);
        }
        fc_accum<true, false><<<gGemm, blk, 0, stream>>>(A, Wfc, bfc, d_out, meta, 0, N);

        // ---- layer 1 ----
        gemm_mfma_f32<128, false><<<gGemm, blk, 0, stream>>>(A, Wp2, B, flag, N);
        agg_gather3<<<gNode8, blk, 0, stream>>>(coff, ecol, dinv, B, b2, A, flag, N);
        fc_accum<false, false><<<gGemm, blk, 0, stream>>>(A, Wfc, bfc, d_out, meta, 1, N);

        // ---- layer 2 ----
        gemm_mfma_f32<128, false><<<gGemm, blk, 0, stream>>>(A, Wp3, B, flag, N);
        agg_gather3<<<gNode8, blk, 0, stream>>>(coff, ecol, dinv, B, b3, A, flag, N);
        fc_accum<false, true><<<gGemm, blk, 0, stream>>>(A, Wfc, bfc, d_out, meta, 2, N);
    } else {
        // ---- tier C: atomic path (round-3 verbatim) ----
        init_deg<<<gN, blk, 0, stream>>>(dinv, odegf, N);
        count_deg<<<gE, blk, 0, stream>>>(row, col, dinv, odegf, E);
        deg_to_dinv<<<gN, blk, 0, stream>>>(dinv, N);

        gemm128<256, true, false><<<gGemm, blk, 0, stream>>>(x, W1, A, flag, N);
        hipMemsetAsync(B, 0, (size_t)NH * 4, stream);
        agg_edges<<<gE2, blk, 0, stream>>>(row, col, dinv, A, B, E);
        finalize_layer<<<gNH, blk, 0, stream>>>(B, A, dinv, b1, B, flag, NH);
        hipMemsetAsync(A, 0, (size_t)NH * 4, stream);
        mean_edges<<<gE2, blk, 0, stream>>>(row, col, B, A, E);
        finalize_mean<<<gNH, blk, 0, stream>>>(A, B, odegf, A, NH);
        fc_accum<true, false><<<gGemm, blk, 0, stream>>>(A, Wfc, bfc, d_out, meta, 0, N);

        gemm128<128, false, false><<<gGemm, blk, 0, stream>>>(A, W2, B, flag, N);
        hipMemsetAsync(A, 0, (size_t)NH * 4, stream);
        agg_edges<<<gE2, blk, 0, stream>>>(row, col, dinv, B, A, E);
        finalize_layer<<<gNH, blk, 0, stream>>>(A, B, dinv, b2, A, flag, NH);
        fc_accum<false, false><<<gGemm, blk, 0, stream>>>(A, Wfc, bfc, d_out, meta, 1, N);

        gemm128<128, false, false><<<gGemm, blk, 0, stream>>>(A, W3, B, flag, N);
        hipMemsetAsync(A, 0, (size_t)NH * 4, stream);
        agg_edges<<<gE2, blk, 0, stream>>>(row, col, dinv, B, A, E);
        finalize_layer<<<gNH, blk, 0, stream>>>(A, B, dinv, b3, A, flag, NH);
        fc_accum<false, true><<<gGemm, blk, 0, stream>>>(A, Wfc, bfc, d_out, meta, 2, N);
    }
}

// Round 9
// 848.925 us; speedup vs baseline: 1.1002x; 1.1002x over previous
//
#include <hip/hip_runtime.h>
#include <hip/hip_bf16.h>

// DynamicJKGCN on MI355X — round 9: shrink aggregation working set.
// Round-8 post-mortem: gather v3 (2x parallelism) was NEUTRAL -> gathers are
// random-row memory-throughput bound, not issue-bound. So: cut bytes/lines per edge.
//  1) GEMM outputs (Hpre) stored bf16 (rows 512B->256B) for the 3 agg passes;
//     aliased into A/B storage (no extra ws). Gather outputs stay fp32.
//  2) CSR indices uint16 (N<65536, guarded) -> scatter2 write churn ~halves.
// Everything else = round 8 (tier C fp32 atomic fallback untouched).

#define H_FEATS 128

typedef __attribute__((ext_vector_type(8))) short short8;   // 8 bf16 in 4 VGPRs
typedef __attribute__((ext_vector_type(4))) float float4v;  // 4 fp32 acc
typedef unsigned short u16;

__device__ __forceinline__ float dload(const void* p, size_t i, int isbf) {
    return isbf ? __bfloat162float(((const __hip_bfloat16*)p)[i])
                : ((const float*)p)[i];
}

__device__ __forceinline__ float4 load4bf(const u16* p) {   // 4 bf16 -> float4 (8B load)
    uint2 u = *(const uint2*)p;
    float4 f;
    f.x = __uint_as_float((u.x & 0xFFFFu) << 16);
    f.y = __uint_as_float(u.x & 0xFFFF0000u);
    f.z = __uint_as_float((u.y & 0xFFFFu) << 16);
    f.w = __uint_as_float(u.y & 0xFFFF0000u);
    return f;
}

__device__ __forceinline__ u16 f2bf(float v) {
    return __bfloat16_as_ushort(__float2bfloat16(v));
}

// ---------------- dtype sniff ----------------
__global__ __launch_bounds__(256) void sniff_dtype(const unsigned int* __restrict__ x,
                                                   int* __restrict__ flag) {
    __shared__ int cnt[256];
    int t = threadIdx.x;
    int c = 0;
    for (int i = 0; i < 16; i++) {
        unsigned int w = x[t * 16 + i];
        unsigned int e = (w >> 7) & 0xFFu;
        c += (e >= 0x60u && e <= 0x8Fu) ? 1 : 0;
    }
    cnt[t] = c;
    __syncthreads();
    for (int s = 128; s > 0; s >>= 1) {
        if (t < s) cnt[t] += cnt[t + s];
        __syncthreads();
    }
    if (t == 0) *flag = (cnt[0] > 3000) ? 1 : 0;
}

// meta[0]=dtype flag (int); meta[8..10]=softmax(jk_weights)
__global__ void compute_jkw(const void* __restrict__ jkwb, float* __restrict__ meta) {
    if (threadIdx.x == 0) {
        int isbf = ((const int*)meta)[0];
        float w0 = dload(jkwb, 0, isbf);
        float w1 = dload(jkwb, 1, isbf);
        float w2 = dload(jkwb, 2, isbf);
        float m = fmaxf(w0, fmaxf(w1, w2));
        float e0 = expf(w0 - m), e1 = expf(w1 - m), e2 = expf(w2 - m);
        float s = e0 + e1 + e2;
        meta[8] = e0 / s; meta[9] = e1 / s; meta[10] = e2 / s;
    }
}

// ---------------- CSR build ----------------
__global__ __launch_bounds__(256) void histo(const int* __restrict__ row, const int* __restrict__ col,
                                             int* __restrict__ cntc, int* __restrict__ cntr, int E) {
    int e = blockIdx.x * 256 + threadIdx.x;
    if (e < E) {
        atomicAdd(&cntc[col[e]], 1);
        atomicAdd(&cntr[row[e]], 1);
    }
}

__global__ __launch_bounds__(256) void dinv_from_cnt(const int* __restrict__ cntc,
                                                     float* __restrict__ dinv, int N) {
    int i = blockIdx.x * 256 + threadIdx.x;
    if (i < N) dinv[i] = rsqrtf(1.0f + (float)cntc[i]);  // +1 self-loop
}

__global__ __launch_bounds__(1024) void scan2(const int* __restrict__ c0, int* __restrict__ o0, int* __restrict__ u0,
                                              const int* __restrict__ c1, int* __restrict__ o1, int* __restrict__ u1,
                                              int N) {
    const int* cnt = blockIdx.x ? c1 : c0;
    int* off = blockIdx.x ? o1 : o0;
    int* cur = blockIdx.x ? u1 : u0;
    __shared__ int part[1024];
    int t = threadIdx.x;
    int chunk = (N + 1023) / 1024;
    int beg = t * chunk;
    int end = beg + chunk; if (end > N) end = N;
    if (beg > N) beg = N;
    int s = 0;
    for (int i = beg; i < end; i++) s += cnt[i];
    part[t] = s;
    __syncthreads();
    for (int d = 1; d < 1024; d <<= 1) {
        int v = (t >= d) ? part[t - d] : 0;
        __syncthreads();
        part[t] += v;
        __syncthreads();
    }
    int base = (t == 0) ? 0 : part[t - 1];
    for (int i = beg; i < end; i++) {
        off[i] = base; cur[i] = base; base += cnt[i];
    }
    if (end == N && beg < N) off[N] = base;
}

// uint16 CSR scatter (valid for N < 65536; launcher guards)
__global__ __launch_bounds__(256) void scatter2u(const int* __restrict__ row, const int* __restrict__ col,
                                                 int* __restrict__ curc, int* __restrict__ curr,
                                                 u16* __restrict__ ecol, u16* __restrict__ erow,
                                                 int E, int doRow) {
    int e = blockIdx.x * 256 + threadIdx.x;
    if (e >= E) return;
    int s = row[e], d = col[e];
    int p = atomicAdd(&curc[d], 1);
    ecol[p] = (u16)s;
    if (doRow) {
        int q = atomicAdd(&curr[s], 1);
        erow[q] = (u16)d;
    }
}

// ---------------- W prepack for MFMA B-fragments (dtype-agnostic) ----------------
__global__ __launch_bounds__(256) void pack_w(const void* __restrict__ W,
                                              u16* __restrict__ Wp,
                                              const int* __restrict__ flagp, int K) {
    int gid = blockIdx.x * 256 + threadIdx.x;
    int steps = K >> 5;
    if (gid >= steps * 8 * 64) return;
    int isbf = *flagp;
    int lane = gid & 63;
    int t = (gid >> 6) & 7;
    int s = gid >> 9;
    int krow = s * 32 + ((lane >> 4) << 3);
    int ncol = t * 16 + (lane & 15);
#pragma unroll
    for (int j = 0; j < 8; j++) {
        float v = dload(W, (size_t)(krow + j) * H_FEATS + ncol, isbf);
        Wp[(size_t)gid * 8 + j] = f2bf(v);
    }
}

// ---------------- MFMA GEMM from fp32 input; fp32 or bf16 output ----------------
template <int K, bool GATED, bool BF16OUT>
__global__ __launch_bounds__(256) void gemm_mfma_f32(const float* __restrict__ X,
                                                     const u16* __restrict__ Wp,
                                                     void* __restrict__ Cv,
                                                     const int* __restrict__ flagp, int M) {
    if (GATED && *flagp != 0) return;
    const int tid = threadIdx.x;
    const int wave = tid >> 6, lane = tid & 63;
    const int m16 = lane & 15, quad = lane >> 4;
    const int row = blockIdx.x * 64 + wave * 16 + m16;
    constexpr int STEPS = K / 32;

    float4v acc[8];
#pragma unroll
    for (int t = 0; t < 8; t++) acc[t] = (float4v){0.f, 0.f, 0.f, 0.f};

    const bool rowOK = row < M;
#pragma unroll
    for (int s = 0; s < STEPS; s++) {
        int k0 = s * 32 + quad * 8;
        short8 a = (short8)(short)0;
        if (rowOK) {
            const float* p = X + (size_t)row * K + k0;
            float4 f0 = *(const float4*)p;
            float4 f1 = *(const float4*)(p + 4);
            a[0] = (short)f2bf(f0.x); a[1] = (short)f2bf(f0.y);
            a[2] = (short)f2bf(f0.z); a[3] = (short)f2bf(f0.w);
            a[4] = (short)f2bf(f1.x); a[5] = (short)f2bf(f1.y);
            a[6] = (short)f2bf(f1.z); a[7] = (short)f2bf(f1.w);
        }
#pragma unroll
        for (int t = 0; t < 8; t++) {
            short8 b = *(const short8*)(Wp + ((size_t)(s * 8 + t) * 64 + lane) * 8);
            acc[t] = __builtin_amdgcn_mfma_f32_16x16x32_bf16(a, b, acc[t], 0, 0, 0);
        }
    }
#pragma unroll
    for (int r = 0; r < 4; r++) {
        int gr = blockIdx.x * 64 + wave * 16 + quad * 4 + r;
        if (gr < M) {
#pragma unroll
            for (int t = 0; t < 8; t++) {
                size_t o = (size_t)gr * H_FEATS + t * 16 + m16;
                if (BF16OUT) ((u16*)Cv)[o] = f2bf(acc[t][r]);
                else         ((float*)Cv)[o] = acc[t][r];
            }
        }
    }
}

// ---------------- gather: half-wave x float4, bf16 H input, u16 idx ----------------
// hout[d] = relu( sum_{s in Nin(d)} dinv[s]dinv[d] H[s] + dinv[d]^2 H[d] + b )  (fp32 out)
__global__ __launch_bounds__(256) void agg_gather3b(const int* __restrict__ off,
                                                    const u16* __restrict__ idx,
                                                    const float* __restrict__ dinv,
                                                    const u16* __restrict__ Hb,
                                                    const void* __restrict__ bv,
                                                    float* __restrict__ hout,
                                                    const int* __restrict__ flagp, int N) {
    int node = blockIdx.x * 8 + (threadIdx.x >> 5);
    if (node >= N) return;
    int l = threadIdx.x & 31;
    int isbf = *flagp;
    int beg = off[node], end = off[node + 1];
    float dd = dinv[node];
    size_t ro = (size_t)l * 4;

    float4 self = load4bf(&Hb[(size_t)node * H_FEATS + ro]);
    float w0s = dd * dd;
    float4 acc = {w0s * self.x, w0s * self.y, w0s * self.z, w0s * self.w};

    int i = beg;
    int s0 = (i < end) ? (int)idx[i] : 0;
    float4 h0 = (i < end) ? load4bf(&Hb[(size_t)s0 * H_FEATS + ro])
                          : (float4){0.f, 0.f, 0.f, 0.f};
    for (; i < end; i++) {
        int s1 = (i + 1 < end) ? (int)idx[i + 1] : 0;
        float4 h1 = (i + 1 < end) ? load4bf(&Hb[(size_t)s1 * H_FEATS + ro]) : h0;
        float w = dinv[s0] * dd;
        acc.x = fmaf(w, h0.x, acc.x);
        acc.y = fmaf(w, h0.y, acc.y);
        acc.z = fmaf(w, h0.z, acc.z);
        acc.w = fmaf(w, h0.w, acc.w);
        s0 = s1; h0 = h1;
    }
    acc.x = fmaxf(acc.x + dload(bv, l * 4 + 0, isbf), 0.0f);
    acc.y = fmaxf(acc.y + dload(bv, l * 4 + 1, isbf), 0.0f);
    acc.z = fmaxf(acc.z + dload(bv, l * 4 + 2, isbf), 0.0f);
    acc.w = fmaxf(acc.w + dload(bv, l * 4 + 3, isbf), 0.0f);
    *(float4*)&hout[(size_t)node * H_FEATS + ro] = acc;
}

// h0[r] = (odeg>0) ? mean_{c in Nout(r)} h0pre[c] : h0pre[r]   (fp32 in/out, u16 idx)
__global__ __launch_bounds__(256) void mean_gather3(const int* __restrict__ off,
                                                    const u16* __restrict__ idx,
                                                    const float* __restrict__ Hsrc,
                                                    float* __restrict__ hout, int N) {
    int node = blockIdx.x * 8 + (threadIdx.x >> 5);
    if (node >= N) return;
    int l = threadIdx.x & 31;
    int beg = off[node], end = off[node + 1];
    size_t ro = (size_t)l * 4;

    float4 acc = {0.f, 0.f, 0.f, 0.f};
    int i = beg;
    int s0 = (i < end) ? (int)idx[i] : 0;
    float4 h0 = (i < end) ? *(const float4*)&Hsrc[(size_t)s0 * H_FEATS + ro]
                          : (float4){0.f, 0.f, 0.f, 0.f};
    for (; i < end; i++) {
        int s1 = (i + 1 < end) ? (int)idx[i + 1] : 0;
        float4 h1 = (i + 1 < end) ? *(const float4*)&Hsrc[(size_t)s1 * H_FEATS + ro] : h0;
        acc.x += h0.x; acc.y += h0.y; acc.z += h0.z; acc.w += h0.w;
        s0 = s1; h0 = h1;
    }
    int cnt = end - beg;
    float4 res;
    if (cnt > 0) {
        float inv = 1.0f / (float)cnt;
        res.x = acc.x * inv; res.y = acc.y * inv; res.z = acc.z * inv; res.w = acc.w * inv;
    } else {
        res = *(const float4*)&Hsrc[(size_t)node * H_FEATS + ro];
    }
    *(float4*)&hout[(size_t)node * H_FEATS + ro] = res;
}

// ---------------- fp32 GEMM (tier C; gated bf16-world path for L0) ----------------
template <int K, bool XIN, bool GATEBF, bool BF16OUT>
__global__ __launch_bounds__(256) void gemm128(const void* __restrict__ Xv,
                                               const void* __restrict__ Wv,
                                               void* __restrict__ Cv,
                                               const int* __restrict__ flagp, int N) {
    constexpr int BM = 64, BK = 16, BN = 128, TN = 8, TX = BN / TN;
    __shared__ float Xs[BK][BM + 4];
    __shared__ float Ws[BK][BN];
    const int isbf = *flagp;
    if (GATEBF && isbf != 1) return;
    const float* Xf = (const float*)Xv;

    const int tid = threadIdx.x;
    const int tx = tid % TX;
    const int ty = tid / TX;
    const int rowBase = blockIdx.x * BM;

    float acc[4][TN] = {};
    const int lk = tid % BK;
    const int lr0 = tid / BK;

    for (int kb = 0; kb < K; kb += BK) {
#pragma unroll
        for (int i = 0; i < 4; i++) {
            int r = lr0 + i * 16;
            int gr = rowBase + r;
            float v = 0.0f;
            if (gr < N) {
                size_t idx = (size_t)gr * K + kb + lk;
                v = XIN ? dload(Xv, idx, isbf) : Xf[idx];
            }
            Xs[lk][r] = v;
        }
#pragma unroll
        for (int i = 0; i < 8; i++) {
            int idx = i * 256 + tid;
            int k = idx >> 7, c = idx & 127;
            Ws[k][c] = dload(Wv, (size_t)(kb + k) * BN + c, isbf);
        }
        __syncthreads();
#pragma unroll
        for (int k = 0; k < BK; k++) {
            float4 a = *(const float4*)&Xs[k][ty * 4];
            float av[4] = {a.x, a.y, a.z, a.w};
            float4 b0 = *(const float4*)&Ws[k][tx * TN];
            float4 b1 = *(const float4*)&Ws[k][tx * TN + 4];
            float bv[8] = {b0.x, b0.y, b0.z, b0.w, b1.x, b1.y, b1.z, b1.w};
#pragma unroll
            for (int i = 0; i < 4; i++)
#pragma unroll
                for (int j = 0; j < TN; j++) acc[i][j] = fmaf(av[i], bv[j], acc[i][j]);
        }
        __syncthreads();
    }
#pragma unroll
    for (int i = 0; i < 4; i++) {
        int gr = rowBase + ty * 4 + i;
        if (gr < N) {
#pragma unroll
            for (int j = 0; j < TN; j++) {
                size_t o = (size_t)gr * BN + tx * TN + j;
                if (BF16OUT) ((u16*)Cv)[o] = f2bf(acc[i][j]);
                else         ((float*)Cv)[o] = acc[i][j];
            }
        }
    }
}

template <bool FIRST, bool LAST>
__global__ __launch_bounds__(256) void fc_accum(const float* __restrict__ Hm,
                                                const void* __restrict__ Wv,
                                                const void* __restrict__ bv,
                                                void* __restrict__ Outv,
                                                const float* __restrict__ meta,
                                                int widx, int N) {
    constexpr int BM = 64, BK = 16, BN = 64, TN = 4, TX = BN / TN, K = 128;
    __shared__ float Xs[BK][BM + 4];
    __shared__ float Ws[BK][BN];
    const int isbf = ((const int*)meta)[0];
    const float scale = meta[8 + widx];

    const int tid = threadIdx.x;
    const int tx = tid % TX;
    const int ty = tid / TX;
    const int rowBase = blockIdx.x * BM;

    float acc[4][TN] = {};
    const int lk = tid % BK;
    const int lr0 = tid / BK;

    for (int kb = 0; kb < K; kb += BK) {
#pragma unroll
        for (int i = 0; i < 4; i++) {
            int r = lr0 + i * 16;
            int gr = rowBase + r;
            float v = 0.0f;
            if (gr < N) v = Hm[(size_t)gr * K + kb + lk];
            Xs[lk][r] = v;
        }
#pragma unroll
        for (int i = 0; i < 4; i++) {
            int idx = i * 256 + tid;
            int k = idx >> 6, c = idx & 63;
            Ws[k][c] = dload(Wv, (size_t)(kb + k) * BN + c, isbf);
        }
        __syncthreads();
#pragma unroll
        for (int k = 0; k < BK; k++) {
            float4 a = *(const float4*)&Xs[k][ty * 4];
            float av[4] = {a.x, a.y, a.z, a.w};
            float4 bb = *(const float4*)&Ws[k][tx * TN];
            float bvv[4] = {bb.x, bb.y, bb.z, bb.w};
#pragma unroll
            for (int i = 0; i < 4; i++)
#pragma unroll
                for (int j = 0; j < TN; j++) acc[i][j] = fmaf(av[i], bvv[j], acc[i][j]);
        }
        __syncthreads();
    }
    __hip_bfloat16* ob = (__hip_bfloat16*)Outv;
    float* of = (float*)Outv;
#pragma unroll
    for (int i = 0; i < 4; i++) {
        int gr = rowBase + ty * 4 + i;
        if (gr < N) {
#pragma unroll
            for (int j = 0; j < TN; j++) {
                int c = tx * TN + j;
                size_t o = (size_t)gr * BN + c;
                float v = scale * acc[i][j];
                if (!FIRST) v += isbf ? __bfloat162float(ob[o]) : of[o];
                if (LAST) v += dload(bv, c, isbf);
                if (isbf) ob[o] = __float2bfloat16(v); else of[o] = v;
            }
        }
    }
}

// ---------------- atomic fallbacks (tier C) ----------------
__global__ __launch_bounds__(256) void init_deg(float* deg, float* odeg, int N) {
    int i = blockIdx.x * 256 + threadIdx.x;
    if (i < N) { deg[i] = 1.0f; odeg[i] = 0.0f; }
}
__global__ __launch_bounds__(256) void count_deg(const int* __restrict__ row, const int* __restrict__ col,
                                                 float* deg, float* odeg, int E) {
    int e = blockIdx.x * 256 + threadIdx.x;
    if (e < E) {
        atomicAdd(&deg[col[e]], 1.0f);
        atomicAdd(&odeg[row[e]], 1.0f);
    }
}
__global__ __launch_bounds__(256) void deg_to_dinv(float* deg, int N) {
    int i = blockIdx.x * 256 + threadIdx.x;
    if (i < N) deg[i] = rsqrtf(deg[i]);
}
__global__ __launch_bounds__(256) void agg_edges(const int* __restrict__ row, const int* __restrict__ col,
                                                 const float* __restrict__ dinv,
                                                 const float* __restrict__ H,
                                                 float* __restrict__ agg, int E) {
    int e = blockIdx.x * 2 + (threadIdx.x >> 7);
    if (e >= E) return;
    int j = threadIdx.x & 127;
    int s = row[e], d = col[e];
    float w = dinv[s] * dinv[d];
    atomicAdd(&agg[(size_t)d * H_FEATS + j], w * H[(size_t)s * H_FEATS + j]);
}
__global__ __launch_bounds__(256) void mean_edges(const int* __restrict__ row, const int* __restrict__ col,
                                                  const float* __restrict__ h0pre,
                                                  float* __restrict__ nsum, int E) {
    int e = blockIdx.x * 2 + (threadIdx.x >> 7);
    if (e >= E) return;
    int j = threadIdx.x & 127;
    int r = row[e], c = col[e];
    atomicAdd(&nsum[(size_t)r * H_FEATS + j], h0pre[(size_t)c * H_FEATS + j]);
}
__global__ __launch_bounds__(256) void finalize_layer(const float* __restrict__ agg,
                                                      const float* __restrict__ H,
                                                      const float* __restrict__ dinv,
                                                      const void* __restrict__ bv,
                                                      float* __restrict__ hout,
                                                      const int* __restrict__ flagp, int NH) {
    int idx = blockIdx.x * 256 + threadIdx.x;
    if (idx >= NH) return;
    int isbf = *flagp;
    int v = idx >> 7, j = idx & 127;
    float di = dinv[v];
    float h = fmaf(di * di, H[idx], agg[idx]) + dload(bv, j, isbf);
    hout[idx] = fmaxf(h, 0.0f);
}
__global__ __launch_bounds__(256) void finalize_mean(const float* __restrict__ nsum,
                                                     const float* __restrict__ h0pre,
                                                     const float* __restrict__ odeg,
                                                     float* __restrict__ h0, int NH) {
    int idx = blockIdx.x * 256 + threadIdx.x;
    if (idx >= NH) return;
    int v = idx >> 7;
    float od = odeg[v];
    h0[idx] = (od > 0.0f) ? (nsum[idx] / od) : h0pre[idx];
}
__global__ __launch_bounds__(256) void finalize_mean_cnt(const float* __restrict__ nsum,
                                                         const float* __restrict__ h0pre,
                                                         const int* __restrict__ cntr,
                                                         float* __restrict__ h0, int NH) {
    int idx = blockIdx.x * 256 + threadIdx.x;
    if (idx >= NH) return;
    int v = idx >> 7;
    int od = cntr[v];
    h0[idx] = (od > 0) ? (nsum[idx] / (float)od) : h0pre[idx];
}

extern "C" void kernel_launch(void* const* d_in, const int* in_sizes, int n_in,
                              void* d_out, int out_size, void* d_ws, size_t ws_size,
                              hipStream_t stream) {
    const void* x   = d_in[0];
    const int*  ei  = (const int*)d_in[1];
    const void* W1  = d_in[2];
    const void* b1  = d_in[3];
    const void* W2  = d_in[4];
    const void* b2  = d_in[5];
    const void* W3  = d_in[6];
    const void* b3  = d_in[7];
    const void* jkb = d_in[8];
    const void* Wfc = d_in[9];
    const void* bfc = d_in[10];

    const int IN = 256;
    const int N = in_sizes[0] / IN;          // 50000
    const int E = in_sizes[1] / 2;           // 800000
    const int NH = N * H_FEATS;

    const int* row = ei;
    const int* col = ei + E;

    // ---- workspace layout (fp32 words) — same footprint as round 7/8 ----
    float* ws = (float*)d_ws;
    size_t o = 0;
    float* meta = ws + o;            o += 256;
    float* dinv = ws + o;            o += N;
    int*   cntc = (int*)(ws + o);    o += N;
    int*   cntr = (int*)(ws + o);    o += N;
    int*   coff = (int*)(ws + o);    o += N + 1;
    int*   curc = (int*)(ws + o);    o += N;
    u16*   ecol = (u16*)(ws + o);    o += E;   // u16 used; slot kept E words
    size_t oB_small = o;
    int*   roff = (int*)(ws + o);    o += N + 1;
    int*   curr = (int*)(ws + o);    o += N;
    u16*   erow = (u16*)(ws + o);    o += E;
    size_t oA_full = o;

    auto alignup = [](size_t v) { return (v + 63) & ~(size_t)63; };
    const size_t WPW = 16384 + 8192 + 8192;
    size_t needA = alignup(oA_full) + 2 * (size_t)NH + 64 + WPW;
    size_t needB = alignup(oB_small) + 2 * (size_t)NH + 64 + WPW;

    int tier;
    size_t hoff;
    if (N >= 65536)                { tier = 2; hoff = alignup(256 + 2 * (size_t)N); } // u16 guard
    else if (ws_size >= needA * 4) { tier = 0; hoff = alignup(oA_full); }
    else if (ws_size >= needB * 4) { tier = 1; hoff = alignup(oB_small); }
    else                           { tier = 2; hoff = alignup(256 + 2 * (size_t)N); }
    float* A = ws + hoff;
    float* B = A + NH;
    u16* HbA = (u16*)A;                       // bf16 Hpre aliased into A storage
    u16* HbB = (u16*)B;                       // bf16 Hpre aliased into B storage
    size_t wpoff = alignup(hoff + 2 * (size_t)NH);
    u16* Wp1 = (u16*)(ws + wpoff);
    u16* Wp2 = Wp1 + 32768;
    u16* Wp3 = Wp2 + 16384;
    float* odegf = ws + 256 + N;
    const int* flag = (const int*)meta;

    dim3 blk(256);
    int gN = (N + 255) / 256;
    int gE = (E + 255) / 256;
    int gE2 = (E + 1) / 2;
    int gNH = (NH + 255) / 256;
    int gGemm = (N + 63) / 64;
    int gNode8 = (N + 7) / 8;

    sniff_dtype<<<1, blk, 0, stream>>>((const unsigned int*)x, (int*)meta);
    compute_jkw<<<1, 64, 0, stream>>>(jkb, meta);

    if (tier < 2) {
        // ---- CSR build (u16 payload) ----
        hipMemsetAsync(cntc, 0, 2 * (size_t)N * 4, stream);
        histo<<<gE, blk, 0, stream>>>(row, col, cntc, cntr, E);
        dinv_from_cnt<<<gN, blk, 0, stream>>>(cntc, dinv, N);
        if (tier == 0) {
            scan2<<<2, 1024, 0, stream>>>(cntc, coff, curc, cntr, roff, curr, N);
            scatter2u<<<gE, blk, 0, stream>>>(row, col, curc, curr, ecol, erow, E, 1);
        } else {
            scan2<<<1, 1024, 0, stream>>>(cntc, coff, curc, cntc, coff, curc, N);
            scatter2u<<<gE, blk, 0, stream>>>(row, col, curc, curc, ecol, ecol, E, 0);
        }

        // ---- W prepack ----
        pack_w<<<16, blk, 0, stream>>>(W1, Wp1, flag, 256);
        pack_w<<<8, blk, 0, stream>>>(W2, Wp2, flag, 128);
        pack_w<<<8, blk, 0, stream>>>(W3, Wp3, flag, 128);

        // ---- layer 0: Hpre0 (bf16) in A storage ----
        gemm128<256, true, true, true><<<gGemm, blk, 0, stream>>>(x, W1, HbA, flag, N);      // bf16 world
        gemm_mfma_f32<256, true, true><<<gGemm, blk, 0, stream>>>((const float*)x, Wp1, HbA, flag, N); // fp32 world
        agg_gather3b<<<gNode8, blk, 0, stream>>>(coff, ecol, dinv, HbA, b1, B, flag, N);     // B = h0pre fp32
        if (tier == 0) {
            mean_gather3<<<gNode8, blk, 0, stream>>>(roff, erow, B, A, N);                   // A = h0 (Hpre0 dead)
        } else {
            hipMemsetAsync(A, 0, (size_t)NH * 4, stream);
            mean_edges<<<gE2, blk, 0, stream>>>(row, col, B, A, E);
            finalize_mean_cnt<<<gNH, blk, 0, stream>>>(A, B, cntr, A, NH);
        }
        fc_accum<true, false><<<gGemm, blk, 0, stream>>>(A, Wfc, bfc, d_out, meta, 0, N);

        // ---- layer 1: Hpre1 (bf16) in B storage (h0pre dead) ----
        gemm_mfma_f32<128, false, true><<<gGemm, blk, 0, stream>>>(A, Wp2, HbB, flag, N);
        agg_gather3b<<<gNode8, blk, 0, stream>>>(coff, ecol, dinv, HbB, b2, A, flag, N);     // A = h1 (h0 dead)
        fc_accum<false, false><<<gGemm, blk, 0, stream>>>(A, Wfc, bfc, d_out, meta, 1, N);

        // ---- layer 2 ----
        gemm_mfma_f32<128, false, true><<<gGemm, blk, 0, stream>>>(A, Wp3, HbB, flag, N);
        agg_gather3b<<<gNode8, blk, 0, stream>>>(coff, ecol, dinv, HbB, b3, A, flag, N);     // A = h2
        fc_accum<false, true><<<gGemm, blk, 0, stream>>>(A, Wfc, bfc, d_out, meta, 2, N);
    } else {
        // ---- tier C: fp32 atomic path (round-3 verbatim) ----
        init_deg<<<gN, blk, 0, stream>>>(dinv, odegf, N);
        count_deg<<<gE, blk, 0, stream>>>(row, col, dinv, odegf, E);
        deg_to_dinv<<<gN, blk, 0, stream>>>(dinv, N);

        gemm128<256, true, false, false><<<gGemm, blk, 0, stream>>>(x, W1, A, flag, N);
        hipMemsetAsync(B, 0, (size_t)NH * 4, stream);
        agg_edges<<<gE2, blk, 0, stream>>>(row, col, dinv, A, B, E);
        finalize_layer<<<gNH, blk, 0, stream>>>(B, A, dinv, b1, B, flag, NH);
        hipMemsetAsync(A, 0, (size_t)NH * 4, stream);
        mean_edges<<<gE2, blk, 0, stream>>>(row, col, B, A, E);
        finalize_mean<<<gNH, blk, 0, stream>>>(A, B, odegf, A, NH);
        fc_accum<true, false><<<gGemm, blk, 0, stream>>>(A, Wfc, bfc, d_out, meta, 0, N);

        gemm128<128, false, false, false><<<gGemm, blk, 0, stream>>>(A, W2, B, flag, N);
        hipMemsetAsync(A, 0, (size_t)NH * 4, stream);
        agg_edges<<<gE2, blk, 0, stream>>>(row, col, dinv, B, A, E);
        finalize_layer<<<gNH, blk, 0, stream>>>(A, B, dinv, b2, A, flag, NH);
        fc_accum<false, false><<<gGemm, blk, 0, stream>>>(A, Wfc, bfc, d_out, meta, 1, N);

        gemm128<128, false, false, false><<<gGemm, blk, 0, stream>>>(A, W3, B, flag, N);
        hipMemsetAsync(A, 0, (size_t)NH * 4, stream);
        agg_edges<<<gE2, blk, 0, stream>>>(row, col, dinv, B, A, E);
        finalize_layer<<<gNH, blk, 0, stream>>>(A, B, dinv, b3, A, flag, NH);
        fc_accum<false, true><<<gGemm, blk, 0, stream>>>(A, Wfc, bfc, d_out, meta, 2, N);
    }
}

// Round 10
// 805.773 us; speedup vs baseline: 1.1591x; 1.0536x over previous
//
#include <hip/hip_runtime.h>
#include <hip/hip_bf16.h>

// DynamicJKGCN on MI355X — round 10: kill scatter write-churn + bf16 mean rows.
// Round-9 post-mortem: u16 CSR payload raised WRITE_SIZE (106->116MB) -> scatter
// is line-churn-bound (zero temporal locality), not payload-bound.
//  1) Destination-tiled scatter: 8 SEQUENTIAL passes; pass t writes only nodes
//     [t*N/8,(t+1)*N/8) -> contiguous ~200KB CSR slice stays L2-resident, lines
//     absorb many writes per write-back. Costs 8x edge-list re-read (~17us).
//  2) h0pre stored bf16 -> mean pass rows 256B (last fp32-row gather).
// Everything else = round 9.

#define H_FEATS 128

typedef __attribute__((ext_vector_type(8))) short short8;
typedef __attribute__((ext_vector_type(4))) float float4v;
typedef unsigned short u16;

__device__ __forceinline__ float dload(const void* p, size_t i, int isbf) {
    return isbf ? __bfloat162float(((const __hip_bfloat16*)p)[i])
                : ((const float*)p)[i];
}

__device__ __forceinline__ float4 load4bf(const u16* p) {
    uint2 u = *(const uint2*)p;
    float4 f;
    f.x = __uint_as_float((u.x & 0xFFFFu) << 16);
    f.y = __uint_as_float(u.x & 0xFFFF0000u);
    f.z = __uint_as_float((u.y & 0xFFFFu) << 16);
    f.w = __uint_as_float(u.y & 0xFFFF0000u);
    return f;
}

__device__ __forceinline__ u16 f2bf(float v) {
    return __bfloat16_as_ushort(__float2bfloat16(v));
}

// ---------------- dtype sniff ----------------
__global__ __launch_bounds__(256) void sniff_dtype(const unsigned int* __restrict__ x,
                                                   int* __restrict__ flag) {
    __shared__ int cnt[256];
    int t = threadIdx.x;
    int c = 0;
    for (int i = 0; i < 16; i++) {
        unsigned int w = x[t * 16 + i];
        unsigned int e = (w >> 7) & 0xFFu;
        c += (e >= 0x60u && e <= 0x8Fu) ? 1 : 0;
    }
    cnt[t] = c;
    __syncthreads();
    for (int s = 128; s > 0; s >>= 1) {
        if (t < s) cnt[t] += cnt[t + s];
        __syncthreads();
    }
    if (t == 0) *flag = (cnt[0] > 3000) ? 1 : 0;
}

__global__ void compute_jkw(const void* __restrict__ jkwb, float* __restrict__ meta) {
    if (threadIdx.x == 0) {
        int isbf = ((const int*)meta)[0];
        float w0 = dload(jkwb, 0, isbf);
        float w1 = dload(jkwb, 1, isbf);
        float w2 = dload(jkwb, 2, isbf);
        float m = fmaxf(w0, fmaxf(w1, w2));
        float e0 = expf(w0 - m), e1 = expf(w1 - m), e2 = expf(w2 - m);
        float s = e0 + e1 + e2;
        meta[8] = e0 / s; meta[9] = e1 / s; meta[10] = e2 / s;
    }
}

// ---------------- CSR build ----------------
__global__ __launch_bounds__(256) void histo(const int* __restrict__ row, const int* __restrict__ col,
                                             int* __restrict__ cntc, int* __restrict__ cntr, int E) {
    int e = blockIdx.x * 256 + threadIdx.x;
    if (e < E) {
        atomicAdd(&cntc[col[e]], 1);
        atomicAdd(&cntr[row[e]], 1);
    }
}

__global__ __launch_bounds__(256) void dinv_from_cnt(const int* __restrict__ cntc,
                                                     float* __restrict__ dinv, int N) {
    int i = blockIdx.x * 256 + threadIdx.x;
    if (i < N) dinv[i] = rsqrtf(1.0f + (float)cntc[i]);
}

__global__ __launch_bounds__(1024) void scan2(const int* __restrict__ c0, int* __restrict__ o0, int* __restrict__ u0,
                                              const int* __restrict__ c1, int* __restrict__ o1, int* __restrict__ u1,
                                              int N) {
    const int* cnt = blockIdx.x ? c1 : c0;
    int* off = blockIdx.x ? o1 : o0;
    int* cur = blockIdx.x ? u1 : u0;
    __shared__ int part[1024];
    int t = threadIdx.x;
    int chunk = (N + 1023) / 1024;
    int beg = t * chunk;
    int end = beg + chunk; if (end > N) end = N;
    if (beg > N) beg = N;
    int s = 0;
    for (int i = beg; i < end; i++) s += cnt[i];
    part[t] = s;
    __syncthreads();
    for (int d = 1; d < 1024; d <<= 1) {
        int v = (t >= d) ? part[t - d] : 0;
        __syncthreads();
        part[t] += v;
        __syncthreads();
    }
    int base = (t == 0) ? 0 : part[t - 1];
    for (int i = beg; i < end; i++) {
        off[i] = base; cur[i] = base; base += cnt[i];
    }
    if (end == N && beg < N) off[N] = base;
}

// destination-tiled scatter: only nodes in [lo,hi) get their CSR entry written.
__global__ __launch_bounds__(256) void scatter_tile(const int* __restrict__ row, const int* __restrict__ col,
                                                    int* __restrict__ curc, int* __restrict__ curr,
                                                    u16* __restrict__ ecol, u16* __restrict__ erow,
                                                    int E, int lo, int hi, int doRow) {
    int e = blockIdx.x * 256 + threadIdx.x;
    if (e >= E) return;
    int s = row[e], d = col[e];
    if (d >= lo && d < hi) {
        int p = atomicAdd(&curc[d], 1);
        ecol[p] = (u16)s;
    }
    if (doRow && s >= lo && s < hi) {
        int q = atomicAdd(&curr[s], 1);
        erow[q] = (u16)d;
    }
}

// ---------------- W prepack ----------------
__global__ __launch_bounds__(256) void pack_w(const void* __restrict__ W,
                                              u16* __restrict__ Wp,
                                              const int* __restrict__ flagp, int K) {
    int gid = blockIdx.x * 256 + threadIdx.x;
    int steps = K >> 5;
    if (gid >= steps * 8 * 64) return;
    int isbf = *flagp;
    int lane = gid & 63;
    int t = (gid >> 6) & 7;
    int s = gid >> 9;
    int krow = s * 32 + ((lane >> 4) << 3);
    int ncol = t * 16 + (lane & 15);
#pragma unroll
    for (int j = 0; j < 8; j++) {
        float v = dload(W, (size_t)(krow + j) * H_FEATS + ncol, isbf);
        Wp[(size_t)gid * 8 + j] = f2bf(v);
    }
}

// ---------------- MFMA GEMM from fp32 input; fp32 or bf16 output ----------------
template <int K, bool GATED, bool BF16OUT>
__global__ __launch_bounds__(256) void gemm_mfma_f32(const float* __restrict__ X,
                                                     const u16* __restrict__ Wp,
                                                     void* __restrict__ Cv,
                                                     const int* __restrict__ flagp, int M) {
    if (GATED && *flagp != 0) return;
    const int tid = threadIdx.x;
    const int wave = tid >> 6, lane = tid & 63;
    const int m16 = lane & 15, quad = lane >> 4;
    const int row = blockIdx.x * 64 + wave * 16 + m16;
    constexpr int STEPS = K / 32;

    float4v acc[8];
#pragma unroll
    for (int t = 0; t < 8; t++) acc[t] = (float4v){0.f, 0.f, 0.f, 0.f};

    const bool rowOK = row < M;
#pragma unroll
    for (int s = 0; s < STEPS; s++) {
        int k0 = s * 32 + quad * 8;
        short8 a = (short8)(short)0;
        if (rowOK) {
            const float* p = X + (size_t)row * K + k0;
            float4 f0 = *(const float4*)p;
            float4 f1 = *(const float4*)(p + 4);
            a[0] = (short)f2bf(f0.x); a[1] = (short)f2bf(f0.y);
            a[2] = (short)f2bf(f0.z); a[3] = (short)f2bf(f0.w);
            a[4] = (short)f2bf(f1.x); a[5] = (short)f2bf(f1.y);
            a[6] = (short)f2bf(f1.z); a[7] = (short)f2bf(f1.w);
        }
#pragma unroll
        for (int t = 0; t < 8; t++) {
            short8 b = *(const short8*)(Wp + ((size_t)(s * 8 + t) * 64 + lane) * 8);
            acc[t] = __builtin_amdgcn_mfma_f32_16x16x32_bf16(a, b, acc[t], 0, 0, 0);
        }
    }
#pragma unroll
    for (int r = 0; r < 4; r++) {
        int gr = blockIdx.x * 64 + wave * 16 + quad * 4 + r;
        if (gr < M) {
#pragma unroll
            for (int t = 0; t < 8; t++) {
                size_t o = (size_t)gr * H_FEATS + t * 16 + m16;
                if (BF16OUT) ((u16*)Cv)[o] = f2bf(acc[t][r]);
                else         ((float*)Cv)[o] = acc[t][r];
            }
        }
    }
}

// ---------------- gather: half-wave x float4, bf16 H input, u16 idx ----------------
template <bool BF16OUT>
__global__ __launch_bounds__(256) void agg_gather3b(const int* __restrict__ off,
                                                    const u16* __restrict__ idx,
                                                    const float* __restrict__ dinv,
                                                    const u16* __restrict__ Hb,
                                                    const void* __restrict__ bv,
                                                    void* __restrict__ houtv,
                                                    const int* __restrict__ flagp, int N) {
    int node = blockIdx.x * 8 + (threadIdx.x >> 5);
    if (node >= N) return;
    int l = threadIdx.x & 31;
    int isbf = *flagp;
    int beg = off[node], end = off[node + 1];
    float dd = dinv[node];
    size_t ro = (size_t)l * 4;

    float4 self = load4bf(&Hb[(size_t)node * H_FEATS + ro]);
    float w0s = dd * dd;
    float4 acc = {w0s * self.x, w0s * self.y, w0s * self.z, w0s * self.w};

    int i = beg;
    int s0 = (i < end) ? (int)idx[i] : 0;
    float4 h0 = (i < end) ? load4bf(&Hb[(size_t)s0 * H_FEATS + ro])
                          : (float4){0.f, 0.f, 0.f, 0.f};
    for (; i < end; i++) {
        int s1 = (i + 1 < end) ? (int)idx[i + 1] : 0;
        float4 h1 = (i + 1 < end) ? load4bf(&Hb[(size_t)s1 * H_FEATS + ro]) : h0;
        float w = dinv[s0] * dd;
        acc.x = fmaf(w, h0.x, acc.x);
        acc.y = fmaf(w, h0.y, acc.y);
        acc.z = fmaf(w, h0.z, acc.z);
        acc.w = fmaf(w, h0.w, acc.w);
        s0 = s1; h0 = h1;
    }
    acc.x = fmaxf(acc.x + dload(bv, l * 4 + 0, isbf), 0.0f);
    acc.y = fmaxf(acc.y + dload(bv, l * 4 + 1, isbf), 0.0f);
    acc.z = fmaxf(acc.z + dload(bv, l * 4 + 2, isbf), 0.0f);
    acc.w = fmaxf(acc.w + dload(bv, l * 4 + 3, isbf), 0.0f);
    if (BF16OUT) {
        u16* hb = (u16*)houtv;
        u16 tmp[4] = {f2bf(acc.x), f2bf(acc.y), f2bf(acc.z), f2bf(acc.w)};
        hb[(size_t)node * H_FEATS + ro + 0] = tmp[0];
        hb[(size_t)node * H_FEATS + ro + 1] = tmp[1];
        hb[(size_t)node * H_FEATS + ro + 2] = tmp[2];
        hb[(size_t)node * H_FEATS + ro + 3] = tmp[3];
    } else {
        *(float4*)&((float*)houtv)[(size_t)node * H_FEATS + ro] = acc;
    }
}

// h0[r] = (odeg>0) ? mean_{c in Nout(r)} h0pre[c] : h0pre[r]  (bf16 in, fp32 out)
__global__ __launch_bounds__(256) void mean_gather3b(const int* __restrict__ off,
                                                     const u16* __restrict__ idx,
                                                     const u16* __restrict__ Hb,
                                                     float* __restrict__ hout, int N) {
    int node = blockIdx.x * 8 + (threadIdx.x >> 5);
    if (node >= N) return;
    int l = threadIdx.x & 31;
    int beg = off[node], end = off[node + 1];
    size_t ro = (size_t)l * 4;

    float4 acc = {0.f, 0.f, 0.f, 0.f};
    int i = beg;
    int s0 = (i < end) ? (int)idx[i] : 0;
    float4 h0 = (i < end) ? load4bf(&Hb[(size_t)s0 * H_FEATS + ro])
                          : (float4){0.f, 0.f, 0.f, 0.f};
    for (; i < end; i++) {
        int s1 = (i + 1 < end) ? (int)idx[i + 1] : 0;
        float4 h1 = (i + 1 < end) ? load4bf(&Hb[(size_t)s1 * H_FEATS + ro]) : h0;
        acc.x += h0.x; acc.y += h0.y; acc.z += h0.z; acc.w += h0.w;
        s0 = s1; h0 = h1;
    }
    int cnt = end - beg;
    float4 res;
    if (cnt > 0) {
        float inv = 1.0f / (float)cnt;
        res.x = acc.x * inv; res.y = acc.y * inv; res.z = acc.z * inv; res.w = acc.w * inv;
    } else {
        res = load4bf(&Hb[(size_t)node * H_FEATS + ro]);
    }
    *(float4*)&hout[(size_t)node * H_FEATS + ro] = res;
}

// ---------------- fp32 GEMM (tier C; gated bf16-world path for L0) ----------------
template <int K, bool XIN, bool GATEBF, bool BF16OUT>
__global__ __launch_bounds__(256) void gemm128(const void* __restrict__ Xv,
                                               const void* __restrict__ Wv,
                                               void* __restrict__ Cv,
                                               const int* __restrict__ flagp, int N) {
    constexpr int BM = 64, BK = 16, BN = 128, TN = 8, TX = BN / TN;
    __shared__ float Xs[BK][BM + 4];
    __shared__ float Ws[BK][BN];
    const int isbf = *flagp;
    if (GATEBF && isbf != 1) return;
    const float* Xf = (const float*)Xv;

    const int tid = threadIdx.x;
    const int tx = tid % TX;
    const int ty = tid / TX;
    const int rowBase = blockIdx.x * BM;

    float acc[4][TN] = {};
    const int lk = tid % BK;
    const int lr0 = tid / BK;

    for (int kb = 0; kb < K; kb += BK) {
#pragma unroll
        for (int i = 0; i < 4; i++) {
            int r = lr0 + i * 16;
            int gr = rowBase + r;
            float v = 0.0f;
            if (gr < N) {
                size_t idx = (size_t)gr * K + kb + lk;
                v = XIN ? dload(Xv, idx, isbf) : Xf[idx];
            }
            Xs[lk][r] = v;
        }
#pragma unroll
        for (int i = 0; i < 8; i++) {
            int idx = i * 256 + tid;
            int k = idx >> 7, c = idx & 127;
            Ws[k][c] = dload(Wv, (size_t)(kb + k) * BN + c, isbf);
        }
        __syncthreads();
#pragma unroll
        for (int k = 0; k < BK; k++) {
            float4 a = *(const float4*)&Xs[k][ty * 4];
            float av[4] = {a.x, a.y, a.z, a.w};
            float4 b0 = *(const float4*)&Ws[k][tx * TN];
            float4 b1 = *(const float4*)&Ws[k][tx * TN + 4];
            float bv[8] = {b0.x, b0.y, b0.z, b0.w, b1.x, b1.y, b1.z, b1.w};
#pragma unroll
            for (int i = 0; i < 4; i++)
#pragma unroll
                for (int j = 0; j < TN; j++) acc[i][j] = fmaf(av[i], bv[j], acc[i][j]);
        }
        __syncthreads();
    }
#pragma unroll
    for (int i = 0; i < 4; i++) {
        int gr = rowBase + ty * 4 + i;
        if (gr < N) {
#pragma unroll
            for (int j = 0; j < TN; j++) {
                size_t o = (size_t)gr * BN + tx * TN + j;
                if (BF16OUT) ((u16*)Cv)[o] = f2bf(acc[i][j]);
                else         ((float*)Cv)[o] = acc[i][j];
            }
        }
    }
}

template <bool FIRST, bool LAST>
__global__ __launch_bounds__(256) void fc_accum(const float* __restrict__ Hm,
                                                const void* __restrict__ Wv,
                                                const void* __restrict__ bv,
                                                void* __restrict__ Outv,
                                                const float* __restrict__ meta,
                                                int widx, int N) {
    constexpr int BM = 64, BK = 16, BN = 64, TN = 4, TX = BN / TN, K = 128;
    __shared__ float Xs[BK][BM + 4];
    __shared__ float Ws[BK][BN];
    const int isbf = ((const int*)meta)[0];
    const float scale = meta[8 + widx];

    const int tid = threadIdx.x;
    const int tx = tid % TX;
    const int ty = tid / TX;
    const int rowBase = blockIdx.x * BM;

    float acc[4][TN] = {};
    const int lk = tid % BK;
    const int lr0 = tid / BK;

    for (int kb = 0; kb < K; kb += BK) {
#pragma unroll
        for (int i = 0; i < 4; i++) {
            int r = lr0 + i * 16;
            int gr = rowBase + r;
            float v = 0.0f;
            if (gr < N) v = Hm[(size_t)gr * K + kb + lk];
            Xs[lk][r] = v;
        }
#pragma unroll
        for (int i = 0; i < 4; i++) {
            int idx = i * 256 + tid;
            int k = idx >> 6, c = idx & 63;
            Ws[k][c] = dload(Wv, (size_t)(kb + k) * BN + c, isbf);
        }
        __syncthreads();
#pragma unroll
        for (int k = 0; k < BK; k++) {
            float4 a = *(const float4*)&Xs[k][ty * 4];
            float av[4] = {a.x, a.y, a.z, a.w};
            float4 bb = *(const float4*)&Ws[k][tx * TN];
            float bvv[4] = {bb.x, bb.y, bb.z, bb.w};
#pragma unroll
            for (int i = 0; i < 4; i++)
#pragma unroll
                for (int j = 0; j < TN; j++) acc[i][j] = fmaf(av[i], bvv[j], acc[i][j]);
        }
        __syncthreads();
    }
    __hip_bfloat16* ob = (__hip_bfloat16*)Outv;
    float* of = (float*)Outv;
#pragma unroll
    for (int i = 0; i < 4; i++) {
        int gr = rowBase + ty * 4 + i;
        if (gr < N) {
#pragma unroll
            for (int j = 0; j < TN; j++) {
                int c = tx * TN + j;
                size_t o = (size_t)gr * BN + c;
                float v = scale * acc[i][j];
                if (!FIRST) v += isbf ? __bfloat162float(ob[o]) : of[o];
                if (LAST) v += dload(bv, c, isbf);
                if (isbf) ob[o] = __float2bfloat16(v); else of[o] = v;
            }
        }
    }
}

// ---------------- atomic fallbacks (tier C) ----------------
__global__ __launch_bounds__(256) void init_deg(float* deg, float* odeg, int N) {
    int i = blockIdx.x * 256 + threadIdx.x;
    if (i < N) { deg[i] = 1.0f; odeg[i] = 0.0f; }
}
__global__ __launch_bounds__(256) void count_deg(const int* __restrict__ row, const int* __restrict__ col,
                                                 float* deg, float* odeg, int E) {
    int e = blockIdx.x * 256 + threadIdx.x;
    if (e < E) {
        atomicAdd(&deg[col[e]], 1.0f);
        atomicAdd(&odeg[row[e]], 1.0f);
    }
}
__global__ __launch_bounds__(256) void deg_to_dinv(float* deg, int N) {
    int i = blockIdx.x * 256 + threadIdx.x;
    if (i < N) deg[i] = rsqrtf(deg[i]);
}
__global__ __launch_bounds__(256) void agg_edges(const int* __restrict__ row, const int* __restrict__ col,
                                                 const float* __restrict__ dinv,
                                                 const float* __restrict__ H,
                                                 float* __restrict__ agg, int E) {
    int e = blockIdx.x * 2 + (threadIdx.x >> 7);
    if (e >= E) return;
    int j = threadIdx.x & 127;
    int s = row[e], d = col[e];
    float w = dinv[s] * dinv[d];
    atomicAdd(&agg[(size_t)d * H_FEATS + j], w * H[(size_t)s * H_FEATS + j]);
}
__global__ __launch_bounds__(256) void mean_edges(const int* __restrict__ row, const int* __restrict__ col,
                                                  const float* __restrict__ h0pre,
                                                  float* __restrict__ nsum, int E) {
    int e = blockIdx.x * 2 + (threadIdx.x >> 7);
    if (e >= E) return;
    int j = threadIdx.x & 127;
    int r = row[e], c = col[e];
    atomicAdd(&nsum[(size_t)r * H_FEATS + j], h0pre[(size_t)c * H_FEATS + j]);
}
__global__ __launch_bounds__(256) void finalize_layer(const float* __restrict__ agg,
                                                      const float* __restrict__ H,
                                                      const float* __restrict__ dinv,
                                                      const void* __restrict__ bv,
                                                      float* __restrict__ hout,
                                                      const int* __restrict__ flagp, int NH) {
    int idx = blockIdx.x * 256 + threadIdx.x;
    if (idx >= NH) return;
    int isbf = *flagp;
    int v = idx >> 7, j = idx & 127;
    float di = dinv[v];
    float h = fmaf(di * di, H[idx], agg[idx]) + dload(bv, j, isbf);
    hout[idx] = fmaxf(h, 0.0f);
}
__global__ __launch_bounds__(256) void finalize_mean(const float* __restrict__ nsum,
                                                     const float* __restrict__ h0pre,
                                                     const float* __restrict__ odeg,
                                                     float* __restrict__ h0, int NH) {
    int idx = blockIdx.x * 256 + threadIdx.x;
    if (idx >= NH) return;
    int v = idx >> 7;
    float od = odeg[v];
    h0[idx] = (od > 0.0f) ? (nsum[idx] / od) : h0pre[idx];
}

extern "C" void kernel_launch(void* const* d_in, const int* in_sizes, int n_in,
                              void* d_out, int out_size, void* d_ws, size_t ws_size,
                              hipStream_t stream) {
    const void* x   = d_in[0];
    const int*  ei  = (const int*)d_in[1];
    const void* W1  = d_in[2];
    const void* b1  = d_in[3];
    const void* W2  = d_in[4];
    const void* b2  = d_in[5];
    const void* W3  = d_in[6];
    const void* b3  = d_in[7];
    const void* jkb = d_in[8];
    const void* Wfc = d_in[9];
    const void* bfc = d_in[10];

    const int IN = 256;
    const int N = in_sizes[0] / IN;          // 50000
    const int E = in_sizes[1] / 2;           // 800000
    const int NH = N * H_FEATS;

    const int* row = ei;
    const int* col = ei + E;

    // ---- workspace layout (fp32 words) — same footprint as round 9 ----
    float* ws = (float*)d_ws;
    size_t o = 0;
    float* meta = ws + o;            o += 256;
    float* dinv = ws + o;            o += N;
    int*   cntc = (int*)(ws + o);    o += N;
    int*   cntr = (int*)(ws + o);    o += N;
    int*   coff = (int*)(ws + o);    o += N + 1;
    int*   curc = (int*)(ws + o);    o += N;
    u16*   ecol = (u16*)(ws + o);    o += E;
    size_t oB_small = o;
    int*   roff = (int*)(ws + o);    o += N + 1;
    int*   curr = (int*)(ws + o);    o += N;
    u16*   erow = (u16*)(ws + o);    o += E;
    size_t oA_full = o;

    auto alignup = [](size_t v) { return (v + 63) & ~(size_t)63; };
    const size_t WPW = 16384 + 8192 + 8192;
    size_t needA = alignup(oA_full) + 2 * (size_t)NH + 64 + WPW;
    size_t needB = alignup(oB_small) + 2 * (size_t)NH + 64 + WPW;

    int tier;
    size_t hoff;
    if (N >= 65536)                { tier = 2; hoff = alignup(256 + 2 * (size_t)N); }
    else if (ws_size >= needA * 4) { tier = 0; hoff = alignup(oA_full); }
    else if (ws_size >= needB * 4) { tier = 1; hoff = alignup(oB_small); }
    else                           { tier = 2; hoff = alignup(256 + 2 * (size_t)N); }
    float* A = ws + hoff;
    float* B = A + NH;
    u16* HbA = (u16*)A;
    u16* HbB = (u16*)B;
    size_t wpoff = alignup(hoff + 2 * (size_t)NH);
    u16* Wp1 = (u16*)(ws + wpoff);
    u16* Wp2 = Wp1 + 32768;
    u16* Wp3 = Wp2 + 16384;
    float* odegf = ws + 256 + N;
    const int* flag = (const int*)meta;

    dim3 blk(256);
    int gN = (N + 255) / 256;
    int gE = (E + 255) / 256;
    int gE2 = (E + 1) / 2;
    int gNH = (NH + 255) / 256;
    int gGemm = (N + 63) / 64;
    int gNode8 = (N + 7) / 8;

    sniff_dtype<<<1, blk, 0, stream>>>((const unsigned int*)x, (int*)meta);
    compute_jkw<<<1, 64, 0, stream>>>(jkb, meta);

    if (tier < 2) {
        // ---- CSR build: histo + scan + 8-pass destination-tiled scatter ----
        hipMemsetAsync(cntc, 0, 2 * (size_t)N * 4, stream);
        histo<<<gE, blk, 0, stream>>>(row, col, cntc, cntr, E);
        dinv_from_cnt<<<gN, blk, 0, stream>>>(cntc, dinv, N);
        const int T = 8;
        int step = (N + T - 1) / T;
        if (tier == 0) {
            scan2<<<2, 1024, 0, stream>>>(cntc, coff, curc, cntr, roff, curr, N);
            for (int t = 0; t < T; t++) {
                int lo = t * step, hi = lo + step; if (hi > N) hi = N;
                scatter_tile<<<gE, blk, 0, stream>>>(row, col, curc, curr, ecol, erow, E, lo, hi, 1);
            }
        } else {
            scan2<<<1, 1024, 0, stream>>>(cntc, coff, curc, cntc, coff, curc, N);
            for (int t = 0; t < T; t++) {
                int lo = t * step, hi = lo + step; if (hi > N) hi = N;
                scatter_tile<<<gE, blk, 0, stream>>>(row, col, curc, curc, ecol, ecol, E, lo, hi, 0);
            }
        }

        // ---- W prepack ----
        pack_w<<<16, blk, 0, stream>>>(W1, Wp1, flag, 256);
        pack_w<<<8, blk, 0, stream>>>(W2, Wp2, flag, 128);
        pack_w<<<8, blk, 0, stream>>>(W3, Wp3, flag, 128);

        // ---- layer 0: Hpre0 bf16 in A; h0pre bf16 in B; h0 fp32 in A ----
        gemm128<256, true, true, true><<<gGemm, blk, 0, stream>>>(x, W1, HbA, flag, N);
        gemm_mfma_f32<256, true, true><<<gGemm, blk, 0, stream>>>((const float*)x, Wp1, HbA, flag, N);
        if (tier == 0) {
            agg_gather3b<true><<<gNode8, blk, 0, stream>>>(coff, ecol, dinv, HbA, b1, HbB, flag, N);  // h0pre bf16
            mean_gather3b<<<gNode8, blk, 0, stream>>>(roff, erow, HbB, A, N);                         // A = h0 fp32
        } else {
            agg_gather3b<false><<<gNode8, blk, 0, stream>>>(coff, ecol, dinv, HbA, b1, B, flag, N);   // B = h0pre fp32
            hipMemsetAsync(A, 0, (size_t)NH * 4, stream);
            mean_edges<<<gE2, blk, 0, stream>>>(row, col, B, A, E);
            // finalize with int counts
            finalize_mean<<<gNH, blk, 0, stream>>>(A, B, odegf, A, NH);  // odegf unused in tier B; fallthrough safe? no —
        }
        fc_accum<true, false><<<gGemm, blk, 0, stream>>>(A, Wfc, bfc, d_out, meta, 0, N);

        // ---- layer 1: Hpre1 bf16 in B (h0pre dead) ----
        gemm_mfma_f32<128, false, true><<<gGemm, blk, 0, stream>>>(A, Wp2, HbB, flag, N);
        agg_gather3b<false><<<gNode8, blk, 0, stream>>>(coff, ecol, dinv, HbB, b2, A, flag, N);       // A = h1 fp32
        fc_accum<false, false><<<gGemm, blk, 0, stream>>>(A, Wfc, bfc, d_out, meta, 1, N);

        // ---- layer 2 ----
        gemm_mfma_f32<128, false, true><<<gGemm, blk, 0, stream>>>(A, Wp3, HbB, flag, N);
        agg_gather3b<false><<<gNode8, blk, 0, stream>>>(coff, ecol, dinv, HbB, b3, A, flag, N);       // A = h2
        fc_accum<false, true><<<gGemm, blk, 0, stream>>>(A, Wfc, bfc, d_out, meta, 2, N);
    } else {
        // ---- tier C: fp32 atomic path ----
        init_deg<<<gN, blk, 0, stream>>>(dinv, odegf, N);
        count_deg<<<gE, blk, 0, stream>>>(row, col, dinv, odegf, E);
        deg_to_dinv<<<gN, blk, 0, stream>>>(dinv, N);

        gemm128<256, true, false, false><<<gGemm, blk, 0, stream>>>(x, W1, A, flag, N);
        hipMemsetAsync(B, 0, (size_t)NH * 4, stream);
        agg_edges<<<gE2, blk, 0, stream>>>(row, col, dinv, A, B, E);
        finalize_layer<<<gNH, blk, 0, stream>>>(B, A, dinv, b1, B, flag, NH);
        hipMemsetAsync(A, 0, (size_t)NH * 4, stream);
        mean_edges<<<gE2, blk, 0, stream>>>(row, col, B, A, E);
        finalize_mean<<<gNH, blk, 0, stream>>>(A, B, odegf, A, NH);
        fc_accum<true, false><<<gGemm, blk, 0, stream>>>(A, Wfc, bfc, d_out, meta, 0, N);

        gemm128<128, false, false, false><<<gGemm, blk, 0, stream>>>(A, W2, B, flag, N);
        hipMemsetAsync(A, 0, (size_t)NH * 4, stream);
        agg_edges<<<gE2, blk, 0, stream>>>(row, col, dinv, B, A, E);
        finalize_layer<<<gNH, blk, 0, stream>>>(A, B, dinv, b2, A, flag, NH);
        fc_accum<false, false><<<gGemm, blk, 0, stream>>>(A, Wfc, bfc, d_out, meta, 1, N);

        gemm128<128, false, false, false><<<gGemm, blk, 0, stream>>>(A, W3, B, flag, N);
        hipMemsetAsync(A, 0, (size_t)NH * 4, stream);
        agg_edges<<<gE2, blk, 0, stream>>>(row, col, dinv, B, A, E);
        finalize_layer<<<gNH, blk, 0, stream>>>(A, B, dinv, b3, A, flag, NH);
        fc_accum<false, true><<<gGemm, blk, 0, stream>>>(A, Wfc, bfc, d_out, meta, 2, N);
    }
}

// Round 11
// 704.467 us; speedup vs baseline: 1.3257x; 1.1438x over previous
//
#include <hip/hip_runtime.h>
#include <hip/hip_bf16.h>

// DynamicJKGCN on MI355X — round 11: parallel hierarchical scan.
// Round-10: 806us; top dispatch = scan2 (112us, 2 blocks, 0.27% occupancy,
// strided uncoalesced). Replace with 3-kernel scan (block sums -> scan sums ->
// block scan + offset), all coalesced int4. Also: tier-B finalize_mean_cnt
// restored (round-10 had int-as-float bug on the never-taken tier-B path).
// Everything else = round 10 (scatter tiling, bf16 rows, MFMA GEMMs).

#define H_FEATS 128

typedef __attribute__((ext_vector_type(8))) short short8;
typedef __attribute__((ext_vector_type(4))) float float4v;
typedef unsigned short u16;

__device__ __forceinline__ float dload(const void* p, size_t i, int isbf) {
    return isbf ? __bfloat162float(((const __hip_bfloat16*)p)[i])
                : ((const float*)p)[i];
}

__device__ __forceinline__ float4 load4bf(const u16* p) {
    uint2 u = *(const uint2*)p;
    float4 f;
    f.x = __uint_as_float((u.x & 0xFFFFu) << 16);
    f.y = __uint_as_float(u.x & 0xFFFF0000u);
    f.z = __uint_as_float((u.y & 0xFFFFu) << 16);
    f.w = __uint_as_float(u.y & 0xFFFF0000u);
    return f;
}

__device__ __forceinline__ u16 f2bf(float v) {
    return __bfloat16_as_ushort(__float2bfloat16(v));
}

// ---------------- dtype sniff ----------------
__global__ __launch_bounds__(256) void sniff_dtype(const unsigned int* __restrict__ x,
                                                   int* __restrict__ flag) {
    __shared__ int cnt[256];
    int t = threadIdx.x;
    int c = 0;
    for (int i = 0; i < 16; i++) {
        unsigned int w = x[t * 16 + i];
        unsigned int e = (w >> 7) & 0xFFu;
        c += (e >= 0x60u && e <= 0x8Fu) ? 1 : 0;
    }
    cnt[t] = c;
    __syncthreads();
    for (int s = 128; s > 0; s >>= 1) {
        if (t < s) cnt[t] += cnt[t + s];
        __syncthreads();
    }
    if (t == 0) *flag = (cnt[0] > 3000) ? 1 : 0;
}

__global__ void compute_jkw(const void* __restrict__ jkwb, float* __restrict__ meta) {
    if (threadIdx.x == 0) {
        int isbf = ((const int*)meta)[0];
        float w0 = dload(jkwb, 0, isbf);
        float w1 = dload(jkwb, 1, isbf);
        float w2 = dload(jkwb, 2, isbf);
        float m = fmaxf(w0, fmaxf(w1, w2));
        float e0 = expf(w0 - m), e1 = expf(w1 - m), e2 = expf(w2 - m);
        float s = e0 + e1 + e2;
        meta[8] = e0 / s; meta[9] = e1 / s; meta[10] = e2 / s;
    }
}

// ---------------- CSR build ----------------
__global__ __launch_bounds__(256) void histo(const int* __restrict__ row, const int* __restrict__ col,
                                             int* __restrict__ cntc, int* __restrict__ cntr, int E) {
    int e = blockIdx.x * 256 + threadIdx.x;
    if (e < E) {
        atomicAdd(&cntc[col[e]], 1);
        atomicAdd(&cntr[row[e]], 1);
    }
}

__global__ __launch_bounds__(256) void dinv_from_cnt(const int* __restrict__ cntc,
                                                     float* __restrict__ dinv, int N) {
    int i = blockIdx.x * 256 + threadIdx.x;
    if (i < N) dinv[i] = rsqrtf(1.0f + (float)cntc[i]);
}

// --- hierarchical scan: K1 block sums (1024 elems/block, int4 coalesced) ---
__global__ __launch_bounds__(256) void scan_bsum(const int* __restrict__ c0, const int* __restrict__ c1,
                                                 int* __restrict__ b0, int* __restrict__ b1, int N) {
    const int* cnt = blockIdx.y ? c1 : c0;
    int* bs = blockIdx.y ? b1 : b0;
    int base = blockIdx.x * 1024 + threadIdx.x * 4;
    int s = 0;
    if (base + 3 < N) {
        int4 v = *(const int4*)&cnt[base];
        s = v.x + v.y + v.z + v.w;
    } else {
        for (int i = 0; i < 4; i++) if (base + i < N) s += cnt[base + i];
    }
    __shared__ int red[256];
    red[threadIdx.x] = s;
    __syncthreads();
    for (int d = 128; d > 0; d >>= 1) {
        if (threadIdx.x < d) red[threadIdx.x] += red[threadIdx.x + d];
        __syncthreads();
    }
    if (threadIdx.x == 0) bs[blockIdx.x] = red[0];
}

// --- K2: exclusive-scan block sums (nb <= 256), write off[N]=total ---
__global__ __launch_bounds__(256) void scan_bsum_scan(int* __restrict__ b0, int* __restrict__ b1,
                                                      int* __restrict__ offN0, int* __restrict__ offN1,
                                                      int nb) {
    int* bs = blockIdx.x ? b1 : b0;
    int* offN = blockIdx.x ? offN1 : offN0;
    __shared__ int sh[256];
    int t = threadIdx.x;
    int v = (t < nb) ? bs[t] : 0;
    sh[t] = v;
    __syncthreads();
    for (int d = 1; d < 256; d <<= 1) {
        int u = (t >= d) ? sh[t - d] : 0;
        __syncthreads();
        sh[t] += u;
        __syncthreads();
    }
    if (t < nb) bs[t] = (t == 0) ? 0 : sh[t - 1];
    if (t == 255) *offN = sh[255];
}

// --- K3: per-block exclusive scan + block offset, int4 in/out ---
__global__ __launch_bounds__(256) void scan_final(const int* __restrict__ c0, const int* __restrict__ c1,
                                                  const int* __restrict__ b0, const int* __restrict__ b1,
                                                  int* __restrict__ o0, int* __restrict__ u0,
                                                  int* __restrict__ o1, int* __restrict__ u1, int N) {
    const int* cnt = blockIdx.y ? c1 : c0;
    const int* bs  = blockIdx.y ? b1 : b0;
    int* off = blockIdx.y ? o1 : o0;
    int* cur = blockIdx.y ? u1 : u0;
    int t = threadIdx.x;
    int base = blockIdx.x * 1024 + t * 4;
    int4 v = {0, 0, 0, 0};
    if (base + 3 < N) {
        v = *(const int4*)&cnt[base];
    } else {
        int tmp[4] = {0, 0, 0, 0};
        for (int i = 0; i < 4; i++) if (base + i < N) tmp[i] = cnt[base + i];
        v.x = tmp[0]; v.y = tmp[1]; v.z = tmp[2]; v.w = tmp[3];
    }
    int s = v.x + v.y + v.z + v.w;
    __shared__ int sh[256];
    sh[t] = s;
    __syncthreads();
    for (int d = 1; d < 256; d <<= 1) {
        int u = (t >= d) ? sh[t - d] : 0;
        __syncthreads();
        sh[t] += u;
        __syncthreads();
    }
    int ex = bs[blockIdx.x] + ((t == 0) ? 0 : sh[t - 1]);
    int4 o;
    o.x = ex; o.y = ex + v.x; o.z = o.y + v.y; o.w = o.z + v.z;
    if (base + 3 < N) {
        *(int4*)&off[base] = o;
        *(int4*)&cur[base] = o;
    } else {
        int arr[4] = {o.x, o.y, o.z, o.w};
        for (int i = 0; i < 4; i++) if (base + i < N) { off[base + i] = arr[i]; cur[base + i] = arr[i]; }
    }
}

// destination-tiled scatter
__global__ __launch_bounds__(256) void scatter_tile(const int* __restrict__ row, const int* __restrict__ col,
                                                    int* __restrict__ curc, int* __restrict__ curr,
                                                    u16* __restrict__ ecol, u16* __restrict__ erow,
                                                    int E, int lo, int hi, int doRow) {
    int e = blockIdx.x * 256 + threadIdx.x;
    if (e >= E) return;
    int s = row[e], d = col[e];
    if (d >= lo && d < hi) {
        int p = atomicAdd(&curc[d], 1);
        ecol[p] = (u16)s;
    }
    if (doRow && s >= lo && s < hi) {
        int q = atomicAdd(&curr[s], 1);
        erow[q] = (u16)d;
    }
}

// ---------------- W prepack ----------------
__global__ __launch_bounds__(256) void pack_w(const void* __restrict__ W,
                                              u16* __restrict__ Wp,
                                              const int* __restrict__ flagp, int K) {
    int gid = blockIdx.x * 256 + threadIdx.x;
    int steps = K >> 5;
    if (gid >= steps * 8 * 64) return;
    int isbf = *flagp;
    int lane = gid & 63;
    int t = (gid >> 6) & 7;
    int s = gid >> 9;
    int krow = s * 32 + ((lane >> 4) << 3);
    int ncol = t * 16 + (lane & 15);
#pragma unroll
    for (int j = 0; j < 8; j++) {
        float v = dload(W, (size_t)(krow + j) * H_FEATS + ncol, isbf);
        Wp[(size_t)gid * 8 + j] = f2bf(v);
    }
}

// ---------------- MFMA GEMM from fp32 input; fp32 or bf16 output ----------------
template <int K, bool GATED, bool BF16OUT>
__global__ __launch_bounds__(256) void gemm_mfma_f32(const float* __restrict__ X,
                                                     const u16* __restrict__ Wp,
                                                     void* __restrict__ Cv,
                                                     const int* __restrict__ flagp, int M) {
    if (GATED && *flagp != 0) return;
    const int tid = threadIdx.x;
    const int wave = tid >> 6, lane = tid & 63;
    const int m16 = lane & 15, quad = lane >> 4;
    const int row = blockIdx.x * 64 + wave * 16 + m16;
    constexpr int STEPS = K / 32;

    float4v acc[8];
#pragma unroll
    for (int t = 0; t < 8; t++) acc[t] = (float4v){0.f, 0.f, 0.f, 0.f};

    const bool rowOK = row < M;
#pragma unroll
    for (int s = 0; s < STEPS; s++) {
        int k0 = s * 32 + quad * 8;
        short8 a = (short8)(short)0;
        if (rowOK) {
            const float* p = X + (size_t)row * K + k0;
            float4 f0 = *(const float4*)p;
            float4 f1 = *(const float4*)(p + 4);
            a[0] = (short)f2bf(f0.x); a[1] = (short)f2bf(f0.y);
            a[2] = (short)f2bf(f0.z); a[3] = (short)f2bf(f0.w);
            a[4] = (short)f2bf(f1.x); a[5] = (short)f2bf(f1.y);
            a[6] = (short)f2bf(f1.z); a[7] = (short)f2bf(f1.w);
        }
#pragma unroll
        for (int t = 0; t < 8; t++) {
            short8 b = *(const short8*)(Wp + ((size_t)(s * 8 + t) * 64 + lane) * 8);
            acc[t] = __builtin_amdgcn_mfma_f32_16x16x32_bf16(a, b, acc[t], 0, 0, 0);
        }
    }
#pragma unroll
    for (int r = 0; r < 4; r++) {
        int gr = blockIdx.x * 64 + wave * 16 + quad * 4 + r;
        if (gr < M) {
#pragma unroll
            for (int t = 0; t < 8; t++) {
                size_t o = (size_t)gr * H_FEATS + t * 16 + m16;
                if (BF16OUT) ((u16*)Cv)[o] = f2bf(acc[t][r]);
                else         ((float*)Cv)[o] = acc[t][r];
            }
        }
    }
}

// ---------------- gather: half-wave x float4, bf16 H input, u16 idx ----------------
template <bool BF16OUT>
__global__ __launch_bounds__(256) void agg_gather3b(const int* __restrict__ off,
                                                    const u16* __restrict__ idx,
                                                    const float* __restrict__ dinv,
                                                    const u16* __restrict__ Hb,
                                                    const void* __restrict__ bv,
                                                    void* __restrict__ houtv,
                                                    const int* __restrict__ flagp, int N) {
    int node = blockIdx.x * 8 + (threadIdx.x >> 5);
    if (node >= N) return;
    int l = threadIdx.x & 31;
    int isbf = *flagp;
    int beg = off[node], end = off[node + 1];
    float dd = dinv[node];
    size_t ro = (size_t)l * 4;

    float4 self = load4bf(&Hb[(size_t)node * H_FEATS + ro]);
    float w0s = dd * dd;
    float4 acc = {w0s * self.x, w0s * self.y, w0s * self.z, w0s * self.w};

    int i = beg;
    int s0 = (i < end) ? (int)idx[i] : 0;
    float4 h0 = (i < end) ? load4bf(&Hb[(size_t)s0 * H_FEATS + ro])
                          : (float4){0.f, 0.f, 0.f, 0.f};
    for (; i < end; i++) {
        int s1 = (i + 1 < end) ? (int)idx[i + 1] : 0;
        float4 h1 = (i + 1 < end) ? load4bf(&Hb[(size_t)s1 * H_FEATS + ro]) : h0;
        float w = dinv[s0] * dd;
        acc.x = fmaf(w, h0.x, acc.x);
        acc.y = fmaf(w, h0.y, acc.y);
        acc.z = fmaf(w, h0.z, acc.z);
        acc.w = fmaf(w, h0.w, acc.w);
        s0 = s1; h0 = h1;
    }
    acc.x = fmaxf(acc.x + dload(bv, l * 4 + 0, isbf), 0.0f);
    acc.y = fmaxf(acc.y + dload(bv, l * 4 + 1, isbf), 0.0f);
    acc.z = fmaxf(acc.z + dload(bv, l * 4 + 2, isbf), 0.0f);
    acc.w = fmaxf(acc.w + dload(bv, l * 4 + 3, isbf), 0.0f);
    if (BF16OUT) {
        u16* hb = (u16*)houtv;
        hb[(size_t)node * H_FEATS + ro + 0] = f2bf(acc.x);
        hb[(size_t)node * H_FEATS + ro + 1] = f2bf(acc.y);
        hb[(size_t)node * H_FEATS + ro + 2] = f2bf(acc.z);
        hb[(size_t)node * H_FEATS + ro + 3] = f2bf(acc.w);
    } else {
        *(float4*)&((float*)houtv)[(size_t)node * H_FEATS + ro] = acc;
    }
}

__global__ __launch_bounds__(256) void mean_gather3b(const int* __restrict__ off,
                                                     const u16* __restrict__ idx,
                                                     const u16* __restrict__ Hb,
                                                     float* __restrict__ hout, int N) {
    int node = blockIdx.x * 8 + (threadIdx.x >> 5);
    if (node >= N) return;
    int l = threadIdx.x & 31;
    int beg = off[node], end = off[node + 1];
    size_t ro = (size_t)l * 4;

    float4 acc = {0.f, 0.f, 0.f, 0.f};
    int i = beg;
    int s0 = (i < end) ? (int)idx[i] : 0;
    float4 h0 = (i < end) ? load4bf(&Hb[(size_t)s0 * H_FEATS + ro])
                          : (float4){0.f, 0.f, 0.f, 0.f};
    for (; i < end; i++) {
        int s1 = (i + 1 < end) ? (int)idx[i + 1] : 0;
        float4 h1 = (i + 1 < end) ? load4bf(&Hb[(size_t)s1 * H_FEATS + ro]) : h0;
        acc.x += h0.x; acc.y += h0.y; acc.z += h0.z; acc.w += h0.w;
        s0 = s1; h0 = h1;
    }
    int cnt = end - beg;
    float4 res;
    if (cnt > 0) {
        float inv = 1.0f / (float)cnt;
        res.x = acc.x * inv; res.y = acc.y * inv; res.z = acc.z * inv; res.w = acc.w * inv;
    } else {
        res = load4bf(&Hb[(size_t)node * H_FEATS + ro]);
    }
    *(float4*)&hout[(size_t)node * H_FEATS + ro] = res;
}

// ---------------- fp32 GEMM (tier C; gated bf16-world path for L0) ----------------
template <int K, bool XIN, bool GATEBF, bool BF16OUT>
__global__ __launch_bounds__(256) void gemm128(const void* __restrict__ Xv,
                                               const void* __restrict__ Wv,
                                               void* __restrict__ Cv,
                                               const int* __restrict__ flagp, int N) {
    constexpr int BM = 64, BK = 16, BN = 128, TN = 8, TX = BN / TN;
    __shared__ float Xs[BK][BM + 4];
    __shared__ float Ws[BK][BN];
    const int isbf = *flagp;
    if (GATEBF && isbf != 1) return;
    const float* Xf = (const float*)Xv;

    const int tid = threadIdx.x;
    const int tx = tid % TX;
    const int ty = tid / TX;
    const int rowBase = blockIdx.x * BM;

    float acc[4][TN] = {};
    const int lk = tid % BK;
    const int lr0 = tid / BK;

    for (int kb = 0; kb < K; kb += BK) {
#pragma unroll
        for (int i = 0; i < 4; i++) {
            int r = lr0 + i * 16;
            int gr = rowBase + r;
            float v = 0.0f;
            if (gr < N) {
                size_t idx = (size_t)gr * K + kb + lk;
                v = XIN ? dload(Xv, idx, isbf) : Xf[idx];
            }
            Xs[lk][r] = v;
        }
#pragma unroll
        for (int i = 0; i < 8; i++) {
            int idx = i * 256 + tid;
            int k = idx >> 7, c = idx & 127;
            Ws[k][c] = dload(Wv, (size_t)(kb + k) * BN + c, isbf);
        }
        __syncthreads();
#pragma unroll
        for (int k = 0; k < BK; k++) {
            float4 a = *(const float4*)&Xs[k][ty * 4];
            float av[4] = {a.x, a.y, a.z, a.w};
            float4 b0 = *(const float4*)&Ws[k][tx * TN];
            float4 b1 = *(const float4*)&Ws[k][tx * TN + 4];
            float bv[8] = {b0.x, b0.y, b0.z, b0.w, b1.x, b1.y, b1.z, b1.w};
#pragma unroll
            for (int i = 0; i < 4; i++)
#pragma unroll
                for (int j = 0; j < TN; j++) acc[i][j] = fmaf(av[i], bv[j], acc[i][j]);
        }
        __syncthreads();
    }
#pragma unroll
    for (int i = 0; i < 4; i++) {
        int gr = rowBase + ty * 4 + i;
        if (gr < N) {
#pragma unroll
            for (int j = 0; j < TN; j++) {
                size_t o = (size_t)gr * BN + tx * TN + j;
                if (BF16OUT) ((u16*)Cv)[o] = f2bf(acc[i][j]);
                else         ((float*)Cv)[o] = acc[i][j];
            }
        }
    }
}

template <bool FIRST, bool LAST>
__global__ __launch_bounds__(256) void fc_accum(const float* __restrict__ Hm,
                                                const void* __restrict__ Wv,
                                                const void* __restrict__ bv,
                                                void* __restrict__ Outv,
                                                const float* __restrict__ meta,
                                                int widx, int N) {
    constexpr int BM = 64, BK = 16, BN = 64, TN = 4, TX = BN / TN, K = 128;
    __shared__ float Xs[BK][BM + 4];
    __shared__ float Ws[BK][BN];
    const int isbf = ((const int*)meta)[0];
    const float scale = meta[8 + widx];

    const int tid = threadIdx.x;
    const int tx = tid % TX;
    const int ty = tid / TX;
    const int rowBase = blockIdx.x * BM;

    float acc[4][TN] = {};
    const int lk = tid % BK;
    const int lr0 = tid / BK;

    for (int kb = 0; kb < K; kb += BK) {
#pragma unroll
        for (int i = 0; i < 4; i++) {
            int r = lr0 + i * 16;
            int gr = rowBase + r;
            float v = 0.0f;
            if (gr < N) v = Hm[(size_t)gr * K + kb + lk];
            Xs[lk][r] = v;
        }
#pragma unroll
        for (int i = 0; i < 4; i++) {
            int idx = i * 256 + tid;
            int k = idx >> 6, c = idx & 63;
            Ws[k][c] = dload(Wv, (size_t)(kb + k) * BN + c, isbf);
        }
        __syncthreads();
#pragma unroll
        for (int k = 0; k < BK; k++) {
            float4 a = *(const float4*)&Xs[k][ty * 4];
            float av[4] = {a.x, a.y, a.z, a.w};
            float4 bb = *(const float4*)&Ws[k][tx * TN];
            float bvv[4] = {bb.x, bb.y, bb.z, bb.w};
#pragma unroll
            for (int i = 0; i < 4; i++)
#pragma unroll
                for (int j = 0; j < TN; j++) acc[i][j] = fmaf(av[i], bvv[j], acc[i][j]);
        }
        __syncthreads();
    }
    __hip_bfloat16* ob = (__hip_bfloat16*)Outv;
    float* of = (float*)Outv;
#pragma unroll
    for (int i = 0; i < 4; i++) {
        int gr = rowBase + ty * 4 + i;
        if (gr < N) {
#pragma unroll
            for (int j = 0; j < TN; j++) {
                int c = tx * TN + j;
                size_t o = (size_t)gr * BN + c;
                float v = scale * acc[i][j];
                if (!FIRST) v += isbf ? __bfloat162float(ob[o]) : of[o];
                if (LAST) v += dload(bv, c, isbf);
                if (isbf) ob[o] = __float2bfloat16(v); else of[o] = v;
            }
        }
    }
}

// ---------------- atomic fallbacks (tier C) ----------------
__global__ __launch_bounds__(256) void init_deg(float* deg, float* odeg, int N) {
    int i = blockIdx.x * 256 + threadIdx.x;
    if (i < N) { deg[i] = 1.0f; odeg[i] = 0.0f; }
}
__global__ __launch_bounds__(256) void count_deg(const int* __restrict__ row, const int* __restrict__ col,
                                                 float* deg, float* odeg, int E) {
    int e = blockIdx.x * 256 + threadIdx.x;
    if (e < E) {
        atomicAdd(&deg[col[e]], 1.0f);
        atomicAdd(&odeg[row[e]], 1.0f);
    }
}
__global__ __launch_bounds__(256) void deg_to_dinv(float* deg, int N) {
    int i = blockIdx.x * 256 + threadIdx.x;
    if (i < N) deg[i] = rsqrtf(deg[i]);
}
__global__ __launch_bounds__(256) void agg_edges(const int* __restrict__ row, const int* __restrict__ col,
                                                 const float* __restrict__ dinv,
                                                 const float* __restrict__ H,
                                                 float* __restrict__ agg, int E) {
    int e = blockIdx.x * 2 + (threadIdx.x >> 7);
    if (e >= E) return;
    int j = threadIdx.x & 127;
    int s = row[e], d = col[e];
    float w = dinv[s] * dinv[d];
    atomicAdd(&agg[(size_t)d * H_FEATS + j], w * H[(size_t)s * H_FEATS + j]);
}
__global__ __launch_bounds__(256) void mean_edges(const int* __restrict__ row, const int* __restrict__ col,
                                                  const float* __restrict__ h0pre,
                                                  float* __restrict__ nsum, int E) {
    int e = blockIdx.x * 2 + (threadIdx.x >> 7);
    if (e >= E) return;
    int j = threadIdx.x & 127;
    int r = row[e], c = col[e];
    atomicAdd(&nsum[(size_t)r * H_FEATS + j], h0pre[(size_t)c * H_FEATS + j]);
}
__global__ __launch_bounds__(256) void finalize_layer(const float* __restrict__ agg,
                                                      const float* __restrict__ H,
                                                      const float* __restrict__ dinv,
                                                      const void* __restrict__ bv,
                                                      float* __restrict__ hout,
                                                      const int* __restrict__ flagp, int NH) {
    int idx = blockIdx.x * 256 + threadIdx.x;
    if (idx >= NH) return;
    int isbf = *flagp;
    int v = idx >> 7, j = idx & 127;
    float di = dinv[v];
    float h = fmaf(di * di, H[idx], agg[idx]) + dload(bv, j, isbf);
    hout[idx] = fmaxf(h, 0.0f);
}
__global__ __launch_bounds__(256) void finalize_mean(const float* __restrict__ nsum,
                                                     const float* __restrict__ h0pre,
                                                     const float* __restrict__ odeg,
                                                     float* __restrict__ h0, int NH) {
    int idx = blockIdx.x * 256 + threadIdx.x;
    if (idx >= NH) return;
    int v = idx >> 7;
    float od = odeg[v];
    h0[idx] = (od > 0.0f) ? (nsum[idx] / od) : h0pre[idx];
}
__global__ __launch_bounds__(256) void finalize_mean_cnt(const float* __restrict__ nsum,
                                                         const float* __restrict__ h0pre,
                                                         const int* __restrict__ cntr,
                                                         float* __restrict__ h0, int NH) {
    int idx = blockIdx.x * 256 + threadIdx.x;
    if (idx >= NH) return;
    int v = idx >> 7;
    int od = cntr[v];
    h0[idx] = (od > 0) ? (nsum[idx] / (float)od) : h0pre[idx];
}

extern "C" void kernel_launch(void* const* d_in, const int* in_sizes, int n_in,
                              void* d_out, int out_size, void* d_ws, size_t ws_size,
                              hipStream_t stream) {
    const void* x   = d_in[0];
    const int*  ei  = (const int*)d_in[1];
    const void* W1  = d_in[2];
    const void* b1  = d_in[3];
    const void* W2  = d_in[4];
    const void* b2  = d_in[5];
    const void* W3  = d_in[6];
    const void* b3  = d_in[7];
    const void* jkb = d_in[8];
    const void* Wfc = d_in[9];
    const void* bfc = d_in[10];

    const int IN = 256;
    const int N = in_sizes[0] / IN;          // 50000
    const int E = in_sizes[1] / 2;           // 800000
    const int NH = N * H_FEATS;

    const int* row = ei;
    const int* col = ei + E;

    // ---- workspace layout (fp32 words); every array start 16B-aligned ----
    auto a4 = [](size_t v) { return (v + 3) & ~(size_t)3; };
    float* ws = (float*)d_ws;
    size_t o = 0;
    float* meta  = ws + o;           o += 256;
    float* dinv  = ws + o;           o += N;          o = a4(o);
    int*   cntc  = (int*)(ws + o);   o += N;          o = a4(o);
    int*   cntr  = (int*)(ws + o);   o += N;          o = a4(o);
    int*   bsumc = (int*)(ws + o);   o += 256;
    int*   bsumr = (int*)(ws + o);   o += 256;
    int*   coff  = (int*)(ws + o);   o += N + 1;      o = a4(o);
    int*   curc  = (int*)(ws + o);   o += N;          o = a4(o);
    u16*   ecol  = (u16*)(ws + o);   o += E;          o = a4(o);
    size_t oB_small = o;
    int*   roff  = (int*)(ws + o);   o += N + 1;      o = a4(o);
    int*   curr  = (int*)(ws + o);   o += N;          o = a4(o);
    u16*   erow  = (u16*)(ws + o);   o += E;          o = a4(o);
    size_t oA_full = o;

    auto alignup = [](size_t v) { return (v + 63) & ~(size_t)63; };
    const size_t WPW = 16384 + 8192 + 8192;
    size_t needA = alignup(oA_full) + 2 * (size_t)NH + 64 + WPW;
    size_t needB = alignup(oB_small) + 2 * (size_t)NH + 64 + WPW;

    int tier;
    size_t hoff;
    if (N >= 65536)                { tier = 2; hoff = alignup(256 + 2 * (size_t)N); }
    else if (ws_size >= needA * 4) { tier = 0; hoff = alignup(oA_full); }
    else if (ws_size >= needB * 4) { tier = 1; hoff = alignup(oB_small); }
    else                           { tier = 2; hoff = alignup(256 + 2 * (size_t)N); }
    float* A = ws + hoff;
    float* B = A + NH;
    u16* HbA = (u16*)A;
    u16* HbB = (u16*)B;
    size_t wpoff = alignup(hoff + 2 * (size_t)NH);
    u16* Wp1 = (u16*)(ws + wpoff);
    u16* Wp2 = Wp1 + 32768;
    u16* Wp3 = Wp2 + 16384;
    float* odegf = ws + 256 + N;     // tier C only (aliases cntc region)
    const int* flag = (const int*)meta;

    dim3 blk(256);
    int gN = (N + 255) / 256;
    int gE = (E + 255) / 256;
    int gE2 = (E + 1) / 2;
    int gNH = (NH + 255) / 256;
    int gGemm = (N + 63) / 64;
    int gNode8 = (N + 7) / 8;
    int nb = (N + 1023) / 1024;      // scan blocks

    sniff_dtype<<<1, blk, 0, stream>>>((const unsigned int*)x, (int*)meta);
    compute_jkw<<<1, 64, 0, stream>>>(jkb, meta);

    if (tier < 2) {
        // ---- CSR build: histo + hierarchical scan + tiled scatter ----
        hipMemsetAsync(cntc, 0, 2 * (size_t)N * 4, stream);
        histo<<<gE, blk, 0, stream>>>(row, col, cntc, cntr, E);
        dinv_from_cnt<<<gN, blk, 0, stream>>>(cntc, dinv, N);
        const int T = 8;
        int step = (N + T - 1) / T;
        if (tier == 0) {
            scan_bsum<<<dim3(nb, 2), blk, 0, stream>>>(cntc, cntr, bsumc, bsumr, N);
            scan_bsum_scan<<<2, blk, 0, stream>>>(bsumc, bsumr, &coff[N], &roff[N], nb);
            scan_final<<<dim3(nb, 2), blk, 0, stream>>>(cntc, cntr, bsumc, bsumr,
                                                        coff, curc, roff, curr, N);
            for (int t = 0; t < T; t++) {
                int lo = t * step, hi = lo + step; if (hi > N) hi = N;
                scatter_tile<<<gE, blk, 0, stream>>>(row, col, curc, curr, ecol, erow, E, lo, hi, 1);
            }
        } else {
            scan_bsum<<<dim3(nb, 1), blk, 0, stream>>>(cntc, cntc, bsumc, bsumc, N);
            scan_bsum_scan<<<1, blk, 0, stream>>>(bsumc, bsumc, &coff[N], &coff[N], nb);
            scan_final<<<dim3(nb, 1), blk, 0, stream>>>(cntc, cntc, bsumc, bsumc,
                                                        coff, curc, coff, curc, N);
            for (int t = 0; t < T; t++) {
                int lo = t * step, hi = lo + step; if (hi > N) hi = N;
                scatter_tile<<<gE, blk, 0, stream>>>(row, col, curc, curc, ecol, ecol, E, lo, hi, 0);
            }
        }

        // ---- W prepack ----
        pack_w<<<16, blk, 0, stream>>>(W1, Wp1, flag, 256);
        pack_w<<<8, blk, 0, stream>>>(W2, Wp2, flag, 128);
        pack_w<<<8, blk, 0, stream>>>(W3, Wp3, flag, 128);

        // ---- layer 0: Hpre0 bf16 in A; h0pre bf16 in B; h0 fp32 in A ----
        gemm128<256, true, true, true><<<gGemm, blk, 0, stream>>>(x, W1, HbA, flag, N);
        gemm_mfma_f32<256, true, true><<<gGemm, blk, 0, stream>>>((const float*)x, Wp1, HbA, flag, N);
        if (tier == 0) {
            agg_gather3b<true><<<gNode8, blk, 0, stream>>>(coff, ecol, dinv, HbA, b1, HbB, flag, N);
            mean_gather3b<<<gNode8, blk, 0, stream>>>(roff, erow, HbB, A, N);
        } else {
            agg_gather3b<false><<<gNode8, blk, 0, stream>>>(coff, ecol, dinv, HbA, b1, B, flag, N);
            hipMemsetAsync(A, 0, (size_t)NH * 4, stream);
            mean_edges<<<gE2, blk, 0, stream>>>(row, col, B, A, E);
            finalize_mean_cnt<<<gNH, blk, 0, stream>>>(A, B, cntr, A, NH);
        }
        fc_accum<true, false><<<gGemm, blk, 0, stream>>>(A, Wfc, bfc, d_out, meta, 0, N);

        // ---- layer 1: Hpre1 bf16 in B ----
        gemm_mfma_f32<128, false, true><<<gGemm, blk, 0, stream>>>(A, Wp2, HbB, flag, N);
        agg_gather3b<false><<<gNode8, blk, 0, stream>>>(coff, ecol, dinv, HbB, b2, A, flag, N);
        fc_accum<false, false><<<gGemm, blk, 0, stream>>>(A, Wfc, bfc, d_out, meta, 1, N);

        // ---- layer 2 ----
        gemm_mfma_f32<128, false, true><<<gGemm, blk, 0, stream>>>(A, Wp3, HbB, flag, N);
        agg_gather3b<false><<<gNode8, blk, 0, stream>>>(coff, ecol, dinv, HbB, b3, A, flag, N);
        fc_accum<false, true><<<gGemm, blk, 0, stream>>>(A, Wfc, bfc, d_out, meta, 2, N);
    } else {
        // ---- tier C: fp32 atomic path ----
        init_deg<<<gN, blk, 0, stream>>>(dinv, odegf, N);
        count_deg<<<gE, blk, 0, stream>>>(row, col, dinv, odegf, E);
        deg_to_dinv<<<gN, blk, 0, stream>>>(dinv, N);

        gemm128<256, true, false, false><<<gGemm, blk, 0, stream>>>(x, W1, A, flag, N);
        hipMemsetAsync(B, 0, (size_t)NH * 4, stream);
        agg_edges<<<gE2, blk, 0, stream>>>(row, col, dinv, A, B, E);
        finalize_layer<<<gNH, blk, 0, stream>>>(B, A, dinv, b1, B, flag, NH);
        hipMemsetAsync(A, 0, (size_t)NH * 4, stream);
        mean_edges<<<gE2, blk, 0, stream>>>(row, col, B, A, E);
        finalize_mean<<<gNH, blk, 0, stream>>>(A, B, odegf, A, NH);
        fc_accum<true, false><<<gGemm, blk, 0, stream>>>(A, Wfc, bfc, d_out, meta, 0, N);

        gemm128<128, false, false, false><<<gGemm, blk, 0, stream>>>(A, W2, B, flag, N);
        hipMemsetAsync(A, 0, (size_t)NH * 4, stream);
        agg_edges<<<gE2, blk, 0, stream>>>(row, col, dinv, B, A, E);
        finalize_layer<<<gNH, blk, 0, stream>>>(A, B, dinv, b2, A, flag, NH);
        fc_accum<false, false><<<gGemm, blk, 0, stream>>>(A, Wfc, bfc, d_out, meta, 1, N);

        gemm128<128, false, false, false><<<gGemm, blk, 0, stream>>>(A, W3, B, flag, N);
        hipMemsetAsync(A, 0, (size_t)NH * 4, stream);
        agg_edges<<<gE2, blk, 0, stream>>>(row, col, dinv, B, A, E);
        finalize_layer<<<gNH, blk, 0, stream>>>(A, B, dinv, b3, A, flag, NH);
        fc_accum<false, true><<<gGemm, blk, 0, stream>>>(A, Wfc, bfc, d_out, meta, 2, N);
    }
}

// Round 12
// 690.187 us; speedup vs baseline: 1.3532x; 1.0207x over previous
//
#include <hip/hip_runtime.h>
#include <hip/hip_bf16.h>

// DynamicJKGCN on MI355X — round 12: bf16 intermediates end-to-end + T=4 scatter.
// Round-11 (704us): agg passes are fabric-bound (~1.4 TB/s random-row path) —
// near structural floor per byte. So cut bytes/passes everywhere else:
//  1) h0pre/h0/h1/h2 stored bf16: agg/mean write bf16, fc reads bf16, L1/L2
//     MFMA reads bf16 A-rows directly (exact — was rounding to bf16 anyway).
//  2) scatter tiles 8->4 (slices still L2-resident, half the edge re-reads).
//  3) sniff+jkw merged (launch diet).
// Tier C (fp32 atomic fallback) untouched.

#define H_FEATS 128

typedef __attribute__((ext_vector_type(8))) short short8;
typedef __attribute__((ext_vector_type(4))) float float4v;
typedef unsigned short u16;

__device__ __forceinline__ float dload(const void* p, size_t i, int isbf) {
    return isbf ? __bfloat162float(((const __hip_bfloat16*)p)[i])
                : ((const float*)p)[i];
}

__device__ __forceinline__ float4 load4bf(const u16* p) {
    uint2 u = *(const uint2*)p;
    float4 f;
    f.x = __uint_as_float((u.x & 0xFFFFu) << 16);
    f.y = __uint_as_float(u.x & 0xFFFF0000u);
    f.z = __uint_as_float((u.y & 0xFFFFu) << 16);
    f.w = __uint_as_float(u.y & 0xFFFF0000u);
    return f;
}

__device__ __forceinline__ u16 f2bf(float v) {
    return __bfloat16_as_ushort(__float2bfloat16(v));
}

// ---------------- dtype sniff + jk softmax (merged) ----------------
__global__ __launch_bounds__(256) void sniff_jkw(const unsigned int* __restrict__ x,
                                                 const void* __restrict__ jkwb,
                                                 float* __restrict__ meta) {
    __shared__ int cnt[256];
    int t = threadIdx.x;
    int c = 0;
    for (int i = 0; i < 16; i++) {
        unsigned int w = x[t * 16 + i];
        unsigned int e = (w >> 7) & 0xFFu;
        c += (e >= 0x60u && e <= 0x8Fu) ? 1 : 0;
    }
    cnt[t] = c;
    __syncthreads();
    for (int s = 128; s > 0; s >>= 1) {
        if (t < s) cnt[t] += cnt[t + s];
        __syncthreads();
    }
    if (t == 0) {
        int isbf = (cnt[0] > 3000) ? 1 : 0;
        ((int*)meta)[0] = isbf;
        float w0 = dload(jkwb, 0, isbf);
        float w1 = dload(jkwb, 1, isbf);
        float w2 = dload(jkwb, 2, isbf);
        float m = fmaxf(w0, fmaxf(w1, w2));
        float e0 = expf(w0 - m), e1 = expf(w1 - m), e2 = expf(w2 - m);
        float s = e0 + e1 + e2;
        meta[8] = e0 / s; meta[9] = e1 / s; meta[10] = e2 / s;
    }
}

// ---------------- CSR build ----------------
__global__ __launch_bounds__(256) void histo(const int* __restrict__ row, const int* __restrict__ col,
                                             int* __restrict__ cntc, int* __restrict__ cntr, int E) {
    int e = blockIdx.x * 256 + threadIdx.x;
    if (e < E) {
        atomicAdd(&cntc[col[e]], 1);
        atomicAdd(&cntr[row[e]], 1);
    }
}

__global__ __launch_bounds__(256) void dinv_from_cnt(const int* __restrict__ cntc,
                                                     float* __restrict__ dinv, int N) {
    int i = blockIdx.x * 256 + threadIdx.x;
    if (i < N) dinv[i] = rsqrtf(1.0f + (float)cntc[i]);
}

__global__ __launch_bounds__(256) void scan_bsum(const int* __restrict__ c0, const int* __restrict__ c1,
                                                 int* __restrict__ b0, int* __restrict__ b1, int N) {
    const int* cnt = blockIdx.y ? c1 : c0;
    int* bs = blockIdx.y ? b1 : b0;
    int base = blockIdx.x * 1024 + threadIdx.x * 4;
    int s = 0;
    if (base + 3 < N) {
        int4 v = *(const int4*)&cnt[base];
        s = v.x + v.y + v.z + v.w;
    } else {
        for (int i = 0; i < 4; i++) if (base + i < N) s += cnt[base + i];
    }
    __shared__ int red[256];
    red[threadIdx.x] = s;
    __syncthreads();
    for (int d = 128; d > 0; d >>= 1) {
        if (threadIdx.x < d) red[threadIdx.x] += red[threadIdx.x + d];
        __syncthreads();
    }
    if (threadIdx.x == 0) bs[blockIdx.x] = red[0];
}

__global__ __launch_bounds__(256) void scan_bsum_scan(int* __restrict__ b0, int* __restrict__ b1,
                                                      int* __restrict__ offN0, int* __restrict__ offN1,
                                                      int nb) {
    int* bs = blockIdx.x ? b1 : b0;
    int* offN = blockIdx.x ? offN1 : offN0;
    __shared__ int sh[256];
    int t = threadIdx.x;
    int v = (t < nb) ? bs[t] : 0;
    sh[t] = v;
    __syncthreads();
    for (int d = 1; d < 256; d <<= 1) {
        int u = (t >= d) ? sh[t - d] : 0;
        __syncthreads();
        sh[t] += u;
        __syncthreads();
    }
    if (t < nb) bs[t] = (t == 0) ? 0 : sh[t - 1];
    if (t == 255) *offN = sh[255];
}

__global__ __launch_bounds__(256) void scan_final(const int* __restrict__ c0, const int* __restrict__ c1,
                                                  const int* __restrict__ b0, const int* __restrict__ b1,
                                                  int* __restrict__ o0, int* __restrict__ u0,
                                                  int* __restrict__ o1, int* __restrict__ u1, int N) {
    const int* cnt = blockIdx.y ? c1 : c0;
    const int* bs  = blockIdx.y ? b1 : b0;
    int* off = blockIdx.y ? o1 : o0;
    int* cur = blockIdx.y ? u1 : u0;
    int t = threadIdx.x;
    int base = blockIdx.x * 1024 + t * 4;
    int4 v = {0, 0, 0, 0};
    if (base + 3 < N) {
        v = *(const int4*)&cnt[base];
    } else {
        int tmp[4] = {0, 0, 0, 0};
        for (int i = 0; i < 4; i++) if (base + i < N) tmp[i] = cnt[base + i];
        v.x = tmp[0]; v.y = tmp[1]; v.z = tmp[2]; v.w = tmp[3];
    }
    int s = v.x + v.y + v.z + v.w;
    __shared__ int sh[256];
    sh[t] = s;
    __syncthreads();
    for (int d = 1; d < 256; d <<= 1) {
        int u = (t >= d) ? sh[t - d] : 0;
        __syncthreads();
        sh[t] += u;
        __syncthreads();
    }
    int ex = bs[blockIdx.x] + ((t == 0) ? 0 : sh[t - 1]);
    int4 o;
    o.x = ex; o.y = ex + v.x; o.z = o.y + v.y; o.w = o.z + v.z;
    if (base + 3 < N) {
        *(int4*)&off[base] = o;
        *(int4*)&cur[base] = o;
    } else {
        int arr[4] = {o.x, o.y, o.z, o.w};
        for (int i = 0; i < 4; i++) if (base + i < N) { off[base + i] = arr[i]; cur[base + i] = arr[i]; }
    }
}

__global__ __launch_bounds__(256) void scatter_tile(const int* __restrict__ row, const int* __restrict__ col,
                                                    int* __restrict__ curc, int* __restrict__ curr,
                                                    u16* __restrict__ ecol, u16* __restrict__ erow,
                                                    int E, int lo, int hi, int doRow) {
    int e = blockIdx.x * 256 + threadIdx.x;
    if (e >= E) return;
    int s = row[e], d = col[e];
    if (d >= lo && d < hi) {
        int p = atomicAdd(&curc[d], 1);
        ecol[p] = (u16)s;
    }
    if (doRow && s >= lo && s < hi) {
        int q = atomicAdd(&curr[s], 1);
        erow[q] = (u16)d;
    }
}

// ---------------- W prepack ----------------
__global__ __launch_bounds__(256) void pack_w(const void* __restrict__ W,
                                              u16* __restrict__ Wp,
                                              const int* __restrict__ flagp, int K) {
    int gid = blockIdx.x * 256 + threadIdx.x;
    int steps = K >> 5;
    if (gid >= steps * 8 * 64) return;
    int isbf = *flagp;
    int lane = gid & 63;
    int t = (gid >> 6) & 7;
    int s = gid >> 9;
    int krow = s * 32 + ((lane >> 4) << 3);
    int ncol = t * 16 + (lane & 15);
#pragma unroll
    for (int j = 0; j < 8; j++) {
        float v = dload(W, (size_t)(krow + j) * H_FEATS + ncol, isbf);
        Wp[(size_t)gid * 8 + j] = f2bf(v);
    }
}

// ---------------- MFMA GEMM; fp32 or bf16 input; fp32 or bf16 output ----------------
template <int K, bool GATED, bool BFIN, bool BF16OUT>
__global__ __launch_bounds__(256) void gemm_mfma(const void* __restrict__ Xv,
                                                 const u16* __restrict__ Wp,
                                                 void* __restrict__ Cv,
                                                 const int* __restrict__ flagp, int M) {
    if (GATED && *flagp != 0) return;
    const int tid = threadIdx.x;
    const int wave = tid >> 6, lane = tid & 63;
    const int m16 = lane & 15, quad = lane >> 4;
    const int row = blockIdx.x * 64 + wave * 16 + m16;
    constexpr int STEPS = K / 32;

    float4v acc[8];
#pragma unroll
    for (int t = 0; t < 8; t++) acc[t] = (float4v){0.f, 0.f, 0.f, 0.f};

    const bool rowOK = row < M;
#pragma unroll
    for (int s = 0; s < STEPS; s++) {
        int k0 = s * 32 + quad * 8;
        short8 a = (short8)(short)0;
        if (rowOK) {
            if (BFIN) {
                a = *(const short8*)((const u16*)Xv + (size_t)row * K + k0);  // bf16 rows, exact
            } else {
                const float* p = (const float*)Xv + (size_t)row * K + k0;
                float4 f0 = *(const float4*)p;
                float4 f1 = *(const float4*)(p + 4);
                a[0] = (short)f2bf(f0.x); a[1] = (short)f2bf(f0.y);
                a[2] = (short)f2bf(f0.z); a[3] = (short)f2bf(f0.w);
                a[4] = (short)f2bf(f1.x); a[5] = (short)f2bf(f1.y);
                a[6] = (short)f2bf(f1.z); a[7] = (short)f2bf(f1.w);
            }
        }
#pragma unroll
        for (int t = 0; t < 8; t++) {
            short8 b = *(const short8*)(Wp + ((size_t)(s * 8 + t) * 64 + lane) * 8);
            acc[t] = __builtin_amdgcn_mfma_f32_16x16x32_bf16(a, b, acc[t], 0, 0, 0);
        }
    }
#pragma unroll
    for (int r = 0; r < 4; r++) {
        int gr = blockIdx.x * 64 + wave * 16 + quad * 4 + r;
        if (gr < M) {
#pragma unroll
            for (int t = 0; t < 8; t++) {
                size_t o = (size_t)gr * H_FEATS + t * 16 + m16;
                if (BF16OUT) ((u16*)Cv)[o] = f2bf(acc[t][r]);
                else         ((float*)Cv)[o] = acc[t][r];
            }
        }
    }
}

// ---------------- gather: half-wave x float4, bf16 H in, bf16/fp32 out ----------------
template <bool BF16OUT>
__global__ __launch_bounds__(256) void agg_gather3b(const int* __restrict__ off,
                                                    const u16* __restrict__ idx,
                                                    const float* __restrict__ dinv,
                                                    const u16* __restrict__ Hb,
                                                    const void* __restrict__ bv,
                                                    void* __restrict__ houtv,
                                                    const int* __restrict__ flagp, int N) {
    int node = blockIdx.x * 8 + (threadIdx.x >> 5);
    if (node >= N) return;
    int l = threadIdx.x & 31;
    int isbf = *flagp;
    int beg = off[node], end = off[node + 1];
    float dd = dinv[node];
    size_t ro = (size_t)l * 4;

    float4 self = load4bf(&Hb[(size_t)node * H_FEATS + ro]);
    float w0s = dd * dd;
    float4 acc = {w0s * self.x, w0s * self.y, w0s * self.z, w0s * self.w};

    int i = beg;
    int s0 = (i < end) ? (int)idx[i] : 0;
    float4 h0 = (i < end) ? load4bf(&Hb[(size_t)s0 * H_FEATS + ro])
                          : (float4){0.f, 0.f, 0.f, 0.f};
    for (; i < end; i++) {
        int s1 = (i + 1 < end) ? (int)idx[i + 1] : 0;
        float4 h1 = (i + 1 < end) ? load4bf(&Hb[(size_t)s1 * H_FEATS + ro]) : h0;
        float w = dinv[s0] * dd;
        acc.x = fmaf(w, h0.x, acc.x);
        acc.y = fmaf(w, h0.y, acc.y);
        acc.z = fmaf(w, h0.z, acc.z);
        acc.w = fmaf(w, h0.w, acc.w);
        s0 = s1; h0 = h1;
    }
    acc.x = fmaxf(acc.x + dload(bv, l * 4 + 0, isbf), 0.0f);
    acc.y = fmaxf(acc.y + dload(bv, l * 4 + 1, isbf), 0.0f);
    acc.z = fmaxf(acc.z + dload(bv, l * 4 + 2, isbf), 0.0f);
    acc.w = fmaxf(acc.w + dload(bv, l * 4 + 3, isbf), 0.0f);
    if (BF16OUT) {
        u16* hb = (u16*)houtv;
        uint2 pk;
        pk.x = (unsigned)f2bf(acc.x) | ((unsigned)f2bf(acc.y) << 16);
        pk.y = (unsigned)f2bf(acc.z) | ((unsigned)f2bf(acc.w) << 16);
        *(uint2*)&hb[(size_t)node * H_FEATS + ro] = pk;
    } else {
        *(float4*)&((float*)houtv)[(size_t)node * H_FEATS + ro] = acc;
    }
}

// h0 = (odeg>0) ? mean h0pre[out-nbrs] : h0pre   (bf16 in, bf16 out)
__global__ __launch_bounds__(256) void mean_gather3b(const int* __restrict__ off,
                                                     const u16* __restrict__ idx,
                                                     const u16* __restrict__ Hb,
                                                     u16* __restrict__ hout, int N) {
    int node = blockIdx.x * 8 + (threadIdx.x >> 5);
    if (node >= N) return;
    int l = threadIdx.x & 31;
    int beg = off[node], end = off[node + 1];
    size_t ro = (size_t)l * 4;

    float4 acc = {0.f, 0.f, 0.f, 0.f};
    int i = beg;
    int s0 = (i < end) ? (int)idx[i] : 0;
    float4 h0 = (i < end) ? load4bf(&Hb[(size_t)s0 * H_FEATS + ro])
                          : (float4){0.f, 0.f, 0.f, 0.f};
    for (; i < end; i++) {
        int s1 = (i + 1 < end) ? (int)idx[i + 1] : 0;
        float4 h1 = (i + 1 < end) ? load4bf(&Hb[(size_t)s1 * H_FEATS + ro]) : h0;
        acc.x += h0.x; acc.y += h0.y; acc.z += h0.z; acc.w += h0.w;
        s0 = s1; h0 = h1;
    }
    int cnt = end - beg;
    float4 res;
    if (cnt > 0) {
        float inv = 1.0f / (float)cnt;
        res.x = acc.x * inv; res.y = acc.y * inv; res.z = acc.z * inv; res.w = acc.w * inv;
    } else {
        res = load4bf(&Hb[(size_t)node * H_FEATS + ro]);
    }
    uint2 pk;
    pk.x = (unsigned)f2bf(res.x) | ((unsigned)f2bf(res.y) << 16);
    pk.y = (unsigned)f2bf(res.z) | ((unsigned)f2bf(res.w) << 16);
    *(uint2*)&hout[(size_t)node * H_FEATS + ro] = pk;
}

// ---------------- fp32 GEMM (tier C; gated bf16-world path for L0) ----------------
template <int K, bool XIN, bool GATEBF, bool BF16OUT>
__global__ __launch_bounds__(256) void gemm128(const void* __restrict__ Xv,
                                               const void* __restrict__ Wv,
                                               void* __restrict__ Cv,
                                               const int* __restrict__ flagp, int N) {
    constexpr int BM = 64, BK = 16, BN = 128, TN = 8, TX = BN / TN;
    __shared__ float Xs[BK][BM + 4];
    __shared__ float Ws[BK][BN];
    const int isbf = *flagp;
    if (GATEBF && isbf != 1) return;
    const float* Xf = (const float*)Xv;

    const int tid = threadIdx.x;
    const int tx = tid % TX;
    const int ty = tid / TX;
    const int rowBase = blockIdx.x * BM;

    float acc[4][TN] = {};
    const int lk = tid % BK;
    const int lr0 = tid / BK;

    for (int kb = 0; kb < K; kb += BK) {
#pragma unroll
        for (int i = 0; i < 4; i++) {
            int r = lr0 + i * 16;
            int gr = rowBase + r;
            float v = 0.0f;
            if (gr < N) {
                size_t idx = (size_t)gr * K + kb + lk;
                v = XIN ? dload(Xv, idx, isbf) : Xf[idx];
            }
            Xs[lk][r] = v;
        }
#pragma unroll
        for (int i = 0; i < 8; i++) {
            int idx = i * 256 + tid;
            int k = idx >> 7, c = idx & 127;
            Ws[k][c] = dload(Wv, (size_t)(kb + k) * BN + c, isbf);
        }
        __syncthreads();
#pragma unroll
        for (int k = 0; k < BK; k++) {
            float4 a = *(const float4*)&Xs[k][ty * 4];
            float av[4] = {a.x, a.y, a.z, a.w};
            float4 b0 = *(const float4*)&Ws[k][tx * TN];
            float4 b1 = *(const float4*)&Ws[k][tx * TN + 4];
            float bv[8] = {b0.x, b0.y, b0.z, b0.w, b1.x, b1.y, b1.z, b1.w};
#pragma unroll
            for (int i = 0; i < 4; i++)
#pragma unroll
                for (int j = 0; j < TN; j++) acc[i][j] = fmaf(av[i], bv[j], acc[i][j]);
        }
        __syncthreads();
    }
#pragma unroll
    for (int i = 0; i < 4; i++) {
        int gr = rowBase + ty * 4 + i;
        if (gr < N) {
#pragma unroll
            for (int j = 0; j < TN; j++) {
                size_t o = (size_t)gr * BN + tx * TN + j;
                if (BF16OUT) ((u16*)Cv)[o] = f2bf(acc[i][j]);
                else         ((float*)Cv)[o] = acc[i][j];
            }
        }
    }
}

template <bool FIRST, bool LAST, bool BFIN>
__global__ __launch_bounds__(256) void fc_accum(const void* __restrict__ Hmv,
                                                const void* __restrict__ Wv,
                                                const void* __restrict__ bv,
                                                void* __restrict__ Outv,
                                                const float* __restrict__ meta,
                                                int widx, int N) {
    constexpr int BM = 64, BK = 16, BN = 64, TN = 4, TX = BN / TN, K = 128;
    __shared__ float Xs[BK][BM + 4];
    __shared__ float Ws[BK][BN];
    const int isbf = ((const int*)meta)[0];
    const float scale = meta[8 + widx];

    const int tid = threadIdx.x;
    const int tx = tid % TX;
    const int ty = tid / TX;
    const int rowBase = blockIdx.x * BM;

    float acc[4][TN] = {};
    const int lk = tid % BK;
    const int lr0 = tid / BK;

    for (int kb = 0; kb < K; kb += BK) {
#pragma unroll
        for (int i = 0; i < 4; i++) {
            int r = lr0 + i * 16;
            int gr = rowBase + r;
            float v = 0.0f;
            if (gr < N) {
                size_t idx = (size_t)gr * K + kb + lk;
                if (BFIN) v = __uint_as_float((unsigned)((const u16*)Hmv)[idx] << 16);
                else      v = ((const float*)Hmv)[idx];
            }
            Xs[lk][r] = v;
        }
#pragma unroll
        for (int i = 0; i < 4; i++) {
            int idx = i * 256 + tid;
            int k = idx >> 6, c = idx & 63;
            Ws[k][c] = dload(Wv, (size_t)(kb + k) * BN + c, isbf);
        }
        __syncthreads();
#pragma unroll
        for (int k = 0; k < BK; k++) {
            float4 a = *(const float4*)&Xs[k][ty * 4];
            float av[4] = {a.x, a.y, a.z, a.w};
            float4 bb = *(const float4*)&Ws[k][tx * TN];
            float bvv[4] = {bb.x, bb.y, bb.z, bb.w};
#pragma unroll
            for (int i = 0; i < 4; i++)
#pragma unroll
                for (int j = 0; j < TN; j++) acc[i][j] = fmaf(av[i], bvv[j], acc[i][j]);
        }
        __syncthreads();
    }
    __hip_bfloat16* ob = (__hip_bfloat16*)Outv;
    float* of = (float*)Outv;
#pragma unroll
    for (int i = 0; i < 4; i++) {
        int gr = rowBase + ty * 4 + i;
        if (gr < N) {
#pragma unroll
            for (int j = 0; j < TN; j++) {
                int c = tx * TN + j;
                size_t o = (size_t)gr * BN + c;
                float v = scale * acc[i][j];
                if (!FIRST) v += isbf ? __bfloat162float(ob[o]) : of[o];
                if (LAST) v += dload(bv, c, isbf);
                if (isbf) ob[o] = __float2bfloat16(v); else of[o] = v;
            }
        }
    }
}

// ---------------- atomic fallbacks (tier B / C) ----------------
__global__ __launch_bounds__(256) void init_deg(float* deg, float* odeg, int N) {
    int i = blockIdx.x * 256 + threadIdx.x;
    if (i < N) { deg[i] = 1.0f; odeg[i] = 0.0f; }
}
__global__ __launch_bounds__(256) void count_deg(const int* __restrict__ row, const int* __restrict__ col,
                                                 float* deg, float* odeg, int E) {
    int e = blockIdx.x * 256 + threadIdx.x;
    if (e < E) {
        atomicAdd(&deg[col[e]], 1.0f);
        atomicAdd(&odeg[row[e]], 1.0f);
    }
}
__global__ __launch_bounds__(256) void deg_to_dinv(float* deg, int N) {
    int i = blockIdx.x * 256 + threadIdx.x;
    if (i < N) deg[i] = rsqrtf(deg[i]);
}
__global__ __launch_bounds__(256) void agg_edges(const int* __restrict__ row, const int* __restrict__ col,
                                                 const float* __restrict__ dinv,
                                                 const float* __restrict__ H,
                                                 float* __restrict__ agg, int E) {
    int e = blockIdx.x * 2 + (threadIdx.x >> 7);
    if (e >= E) return;
    int j = threadIdx.x & 127;
    int s = row[e], d = col[e];
    float w = dinv[s] * dinv[d];
    atomicAdd(&agg[(size_t)d * H_FEATS + j], w * H[(size_t)s * H_FEATS + j]);
}
__global__ __launch_bounds__(256) void mean_edges(const int* __restrict__ row, const int* __restrict__ col,
                                                  const float* __restrict__ h0pre,
                                                  float* __restrict__ nsum, int E) {
    int e = blockIdx.x * 2 + (threadIdx.x >> 7);
    if (e >= E) return;
    int j = threadIdx.x & 127;
    int r = row[e], c = col[e];
    atomicAdd(&nsum[(size_t)r * H_FEATS + j], h0pre[(size_t)c * H_FEATS + j]);
}
__global__ __launch_bounds__(256) void finalize_layer(const float* __restrict__ agg,
                                                      const float* __restrict__ H,
                                                      const float* __restrict__ dinv,
                                                      const void* __restrict__ bv,
                                                      float* __restrict__ hout,
                                                      const int* __restrict__ flagp, int NH) {
    int idx = blockIdx.x * 256 + threadIdx.x;
    if (idx >= NH) return;
    int isbf = *flagp;
    int v = idx >> 7, j = idx & 127;
    float di = dinv[v];
    float h = fmaf(di * di, H[idx], agg[idx]) + dload(bv, j, isbf);
    hout[idx] = fmaxf(h, 0.0f);
}
__global__ __launch_bounds__(256) void finalize_mean(const float* __restrict__ nsum,
                                                     const float* __restrict__ h0pre,
                                                     const float* __restrict__ odeg,
                                                     float* __restrict__ h0, int NH) {
    int idx = blockIdx.x * 256 + threadIdx.x;
    if (idx >= NH) return;
    int v = idx >> 7;
    float od = odeg[v];
    h0[idx] = (od > 0.0f) ? (nsum[idx] / od) : h0pre[idx];
}
__global__ __launch_bounds__(256) void finalize_mean_cnt(const float* __restrict__ nsum,
                                                         const float* __restrict__ h0pre,
                                                         const int* __restrict__ cntr,
                                                         float* __restrict__ h0, int NH) {
    int idx = blockIdx.x * 256 + threadIdx.x;
    if (idx >= NH) return;
    int v = idx >> 7;
    int od = cntr[v];
    h0[idx] = (od > 0) ? (nsum[idx] / (float)od) : h0pre[idx];
}

extern "C" void kernel_launch(void* const* d_in, const int* in_sizes, int n_in,
                              void* d_out, int out_size, void* d_ws, size_t ws_size,
                              hipStream_t stream) {
    const void* x   = d_in[0];
    const int*  ei  = (const int*)d_in[1];
    const void* W1  = d_in[2];
    const void* b1  = d_in[3];
    const void* W2  = d_in[4];
    const void* b2  = d_in[5];
    const void* W3  = d_in[6];
    const void* b3  = d_in[7];
    const void* jkb = d_in[8];
    const void* Wfc = d_in[9];
    const void* bfc = d_in[10];

    const int IN = 256;
    const int N = in_sizes[0] / IN;          // 50000
    const int E = in_sizes[1] / 2;           // 800000
    const int NH = N * H_FEATS;

    const int* row = ei;
    const int* col = ei + E;

    // ---- workspace layout (fp32 words); arrays 16B-aligned ----
    auto a4 = [](size_t v) { return (v + 3) & ~(size_t)3; };
    float* ws = (float*)d_ws;
    size_t o = 0;
    float* meta  = ws + o;           o += 256;
    float* dinv  = ws + o;           o += N;          o = a4(o);
    int*   cntc  = (int*)(ws + o);   o += N;          o = a4(o);
    int*   cntr  = (int*)(ws + o);   o += N;          o = a4(o);
    int*   bsumc = (int*)(ws + o);   o += 256;
    int*   bsumr = (int*)(ws + o);   o += 256;
    int*   coff  = (int*)(ws + o);   o += N + 1;      o = a4(o);
    int*   curc  = (int*)(ws + o);   o += N;          o = a4(o);
    u16*   ecol  = (u16*)(ws + o);   o += E;          o = a4(o);
    size_t oB_small = o;
    int*   roff  = (int*)(ws + o);   o += N + 1;      o = a4(o);
    int*   curr  = (int*)(ws + o);   o += N;          o = a4(o);
    u16*   erow  = (u16*)(ws + o);   o += E;          o = a4(o);
    size_t oA_full = o;

    auto alignup = [](size_t v) { return (v + 63) & ~(size_t)63; };
    const size_t WPW = 16384 + 8192 + 8192;
    size_t needA = alignup(oA_full) + 2 * (size_t)NH + 64 + WPW;
    size_t needB = alignup(oB_small) + 2 * (size_t)NH + 64 + WPW;

    int tier;
    size_t hoff;
    if (N >= 65536)                { tier = 2; hoff = alignup(256 + 2 * (size_t)N); }
    else if (ws_size >= needA * 4) { tier = 0; hoff = alignup(oA_full); }
    else if (ws_size >= needB * 4) { tier = 1; hoff = alignup(oB_small); }
    else                           { tier = 2; hoff = alignup(256 + 2 * (size_t)N); }
    float* A = ws + hoff;
    float* B = A + NH;
    u16* HbA = (u16*)A;
    u16* HbB = (u16*)B;
    size_t wpoff = alignup(hoff + 2 * (size_t)NH);
    u16* Wp1 = (u16*)(ws + wpoff);
    u16* Wp2 = Wp1 + 32768;
    u16* Wp3 = Wp2 + 16384;
    float* odegf = ws + 256 + N;
    const int* flag = (const int*)meta;

    dim3 blk(256);
    int gN = (N + 255) / 256;
    int gE = (E + 255) / 256;
    int gE2 = (E + 1) / 2;
    int gNH = (NH + 255) / 256;
    int gGemm = (N + 63) / 64;
    int gNode8 = (N + 7) / 8;
    int nb = (N + 1023) / 1024;

    sniff_jkw<<<1, blk, 0, stream>>>((const unsigned int*)x, jkb, meta);

    if (tier < 2) {
        // ---- CSR build ----
        hipMemsetAsync(cntc, 0, 2 * (size_t)N * 4, stream);
        histo<<<gE, blk, 0, stream>>>(row, col, cntc, cntr, E);
        dinv_from_cnt<<<gN, blk, 0, stream>>>(cntc, dinv, N);
        const int T = 4;
        int step = (N + T - 1) / T;
        if (tier == 0) {
            scan_bsum<<<dim3(nb, 2), blk, 0, stream>>>(cntc, cntr, bsumc, bsumr, N);
            scan_bsum_scan<<<2, blk, 0, stream>>>(bsumc, bsumr, &coff[N], &roff[N], nb);
            scan_final<<<dim3(nb, 2), blk, 0, stream>>>(cntc, cntr, bsumc, bsumr,
                                                        coff, curc, roff, curr, N);
            for (int t = 0; t < T; t++) {
                int lo = t * step, hi = lo + step; if (hi > N) hi = N;
                scatter_tile<<<gE, blk, 0, stream>>>(row, col, curc, curr, ecol, erow, E, lo, hi, 1);
            }
        } else {
            scan_bsum<<<dim3(nb, 1), blk, 0, stream>>>(cntc, cntc, bsumc, bsumc, N);
            scan_bsum_scan<<<1, blk, 0, stream>>>(bsumc, bsumc, &coff[N], &coff[N], nb);
            scan_final<<<dim3(nb, 1), blk, 0, stream>>>(cntc, cntc, bsumc, bsumc,
                                                        coff, curc, coff, curc, N);
            for (int t = 0; t < T; t++) {
                int lo = t * step, hi = lo + step; if (hi > N) hi = N;
                scatter_tile<<<gE, blk, 0, stream>>>(row, col, curc, curc, ecol, ecol, E, lo, hi, 0);
            }
        }

        // ---- W prepack ----
        pack_w<<<16, blk, 0, stream>>>(W1, Wp1, flag, 256);
        pack_w<<<8, blk, 0, stream>>>(W2, Wp2, flag, 128);
        pack_w<<<8, blk, 0, stream>>>(W3, Wp3, flag, 128);

        // ---- layer 0: Hpre0 bf16 in A ----
        gemm128<256, true, true, true><<<gGemm, blk, 0, stream>>>(x, W1, HbA, flag, N);
        gemm_mfma<256, true, false, true><<<gGemm, blk, 0, stream>>>(x, Wp1, HbA, flag, N);
        if (tier == 0) {
            agg_gather3b<true><<<gNode8, blk, 0, stream>>>(coff, ecol, dinv, HbA, b1, HbB, flag, N);  // h0pre bf16 in B
            mean_gather3b<<<gNode8, blk, 0, stream>>>(roff, erow, HbB, HbA, N);                       // h0 bf16 in A
            fc_accum<true, false, true><<<gGemm, blk, 0, stream>>>(HbA, Wfc, bfc, d_out, meta, 0, N);

            // ---- layer 1: h0 bf16 -> Hpre1 bf16 in B (exact bf16 A-read) ----
            gemm_mfma<128, false, true, true><<<gGemm, blk, 0, stream>>>(HbA, Wp2, HbB, flag, N);
            agg_gather3b<true><<<gNode8, blk, 0, stream>>>(coff, ecol, dinv, HbB, b2, HbA, flag, N);  // h1 bf16 in A
            fc_accum<false, false, true><<<gGemm, blk, 0, stream>>>(HbA, Wfc, bfc, d_out, meta, 1, N);

            // ---- layer 2 ----
            gemm_mfma<128, false, true, true><<<gGemm, blk, 0, stream>>>(HbA, Wp3, HbB, flag, N);
            agg_gather3b<true><<<gNode8, blk, 0, stream>>>(coff, ecol, dinv, HbB, b3, HbA, flag, N);  // h2 bf16 in A
            fc_accum<false, true, true><<<gGemm, blk, 0, stream>>>(HbA, Wfc, bfc, d_out, meta, 2, N);
        } else {
            // tier B: fp32 intermediates via atomic mean path
            agg_gather3b<false><<<gNode8, blk, 0, stream>>>(coff, ecol, dinv, HbA, b1, B, flag, N);   // h0pre fp32 in B
            hipMemsetAsync(A, 0, (size_t)NH * 4, stream);
            mean_edges<<<gE2, blk, 0, stream>>>(row, col, B, A, E);
            finalize_mean_cnt<<<gNH, blk, 0, stream>>>(A, B, cntr, A, NH);                            // h0 fp32 in A
            fc_accum<true, false, false><<<gGemm, blk, 0, stream>>>(A, Wfc, bfc, d_out, meta, 0, N);

            gemm_mfma<128, false, false, true><<<gGemm, blk, 0, stream>>>(A, Wp2, HbB, flag, N);
            agg_gather3b<true><<<gNode8, blk, 0, stream>>>(coff, ecol, dinv, HbB, b2, HbA, flag, N);
            fc_accum<false, false, true><<<gGemm, blk, 0, stream>>>(HbA, Wfc, bfc, d_out, meta, 1, N);

            gemm_mfma<128, false, true, true><<<gGemm, blk, 0, stream>>>(HbA, Wp3, HbB, flag, N);
            agg_gather3b<true><<<gNode8, blk, 0, stream>>>(coff, ecol, dinv, HbB, b3, HbA, flag, N);
            fc_accum<false, true, true><<<gGemm, blk, 0, stream>>>(HbA, Wfc, bfc, d_out, meta, 2, N);
        }
    } else {
        // ---- tier C: fp32 atomic path ----
        init_deg<<<gN, blk, 0, stream>>>(dinv, odegf, N);
        count_deg<<<gE, blk, 0, stream>>>(row, col, dinv, odegf, E);
        deg_to_dinv<<<gN, blk, 0, stream>>>(dinv, N);

        gemm128<256, true, false, false><<<gGemm, blk, 0, stream>>>(x, W1, A, flag, N);
        hipMemsetAsync(B, 0, (size_t)NH * 4, stream);
        agg_edges<<<gE2, blk, 0, stream>>>(row, col, dinv, A, B, E);
        finalize_layer<<<gNH, blk, 0, stream>>>(B, A, dinv, b1, B, flag, NH);
        hipMemsetAsync(A, 0, (size_t)NH * 4, stream);
        mean_edges<<<gE2, blk, 0, stream>>>(row, col, B, A, E);
        finalize_mean<<<gNH, blk, 0, stream>>>(A, B, odegf, A, NH);
        fc_accum<true, false, false><<<gGemm, blk, 0, stream>>>(A, Wfc, bfc, d_out, meta, 0, N);

        gemm128<128, false, false, false><<<gGemm, blk, 0, stream>>>(A, W2, B, flag, N);
        hipMemsetAsync(A, 0, (size_t)NH * 4, stream);
        agg_edges<<<gE2, blk, 0, stream>>>(row, col, dinv, B, A, E);
        finalize_layer<<<gNH, blk, 0, stream>>>(A, B, dinv, b2, A, flag, NH);
        fc_accum<false, false, false><<<gGemm, blk, 0, stream>>>(A, Wfc, bfc, d_out, meta, 1, N);

        gemm128<128, false, false, false><<<gGemm, blk, 0, stream>>>(A, W3, B, flag, N);
        hipMemsetAsync(A, 0, (size_t)NH * 4, stream);
        agg_edges<<<gE2, blk, 0, stream>>>(row, col, dinv, B, A, E);
        finalize_layer<<<gNH, blk, 0, stream>>>(A, B, dinv, b3, A, flag, NH);
        fc_accum<false, true, false><<<gGemm, blk, 0, stream>>>(A, Wfc, bfc, d_out, meta, 2, N);
    }
}